// Round 1
// baseline (696.063 us; speedup 1.0000x reference)
//
#include <hip/hip_runtime.h>
#include <hip/hip_bf16.h>

static constexpr int NN    = 50000;
static constexpr int FIN   = 1433;
static constexpr int KPAD  = 1440;   // 45 * 32
static constexpr int KFULL = 44;     // full 32-wide k-steps (44*32 = 1408)

typedef __bf16 bf16x8 __attribute__((ext_vector_type(8)));
typedef float  f32x4  __attribute__((ext_vector_type(4)));

__device__ __forceinline__ float leaky02(float v){ return v >= 0.f ? v : 0.2f * v; }

// ---------------- CSR build ----------------
__global__ __launch_bounds__(256) void k_hist(const int* __restrict__ dst, int* __restrict__ deg, int E){
    int e = blockIdx.x * 256 + threadIdx.x;
    if (e < E) atomicAdd(&deg[dst[e]], 1);
}

__global__ __launch_bounds__(1024) void k_scan(const int* __restrict__ deg,
                                               int* __restrict__ row_off, int* __restrict__ cursor){
    __shared__ int sums[1024];
    const int PER = (NN + 1023) / 1024;   // 49
    int t = threadIdx.x;
    int base = t * PER;
    int local = 0;
    for (int i = 0; i < PER; ++i){ int idx = base + i; if (idx < NN) local += deg[idx]; }
    sums[t] = local;
    __syncthreads();
    for (int off = 1; off < 1024; off <<= 1){
        int v = sums[t];
        int add = (t >= off) ? sums[t - off] : 0;
        __syncthreads();
        sums[t] = v + add;
        __syncthreads();
    }
    int carry = (t > 0) ? sums[t - 1] : 0;
    for (int i = 0; i < PER; ++i){
        int idx = base + i;
        if (idx < NN){ row_off[idx] = carry; cursor[idx] = carry; carry += deg[idx]; }
    }
    if (t == 1023) row_off[NN] = carry;
}

__global__ __launch_bounds__(256) void k_scatter(const int* __restrict__ src, const int* __restrict__ dst,
                                                 int* __restrict__ cursor, int* __restrict__ csr, int E){
    int e = blockIdx.x * 256 + threadIdx.x;
    if (e < E){
        int d = dst[e];
        int pos = atomicAdd(&cursor[d], 1);
        csr[pos] = src[e];
    }
}

// ---------------- W1 transpose + bf16 split (hi/lo planes) ----------------
__global__ __launch_bounds__(256) void k_w1t(const float* __restrict__ W1,
                                             __bf16* __restrict__ w1h, __bf16* __restrict__ w1l){
    int c = blockIdx.x;                       // 0..63 output column
    for (int k = threadIdx.x; k < KPAD; k += 256){
        float v = (k < FIN) ? W1[(size_t)k * 64 + c] : 0.f;
        __bf16 hi = (__bf16)v;
        w1h[(size_t)c * KPAD + k] = hi;
        w1l[(size_t)c * KPAD + k] = (__bf16)(v - (float)hi);
    }
}

// ---------------- GEMM1: H = x @ W1 (split-bf16 MFMA, f32 accuracy) ----------------
template<bool TAIL>
__device__ __forceinline__ void gemm1_step(const float* __restrict__ xk, int k0, int lk,
    const __bf16* __restrict__ bhb, const __bf16* __restrict__ blb,
    f32x4& a0, f32x4& a1, f32x4& a2, f32x4& a3)
{
    float av[8];
    #pragma unroll
    for (int e = 0; e < 8; ++e){
        av[e] = (!TAIL || (k0 + lk * 8 + e < FIN)) ? xk[k0 + e] : 0.f;
    }
    bf16x8 ah, al;
    #pragma unroll
    for (int e = 0; e < 8; ++e){
        __bf16 hi = (__bf16)av[e];
        ah[e] = hi;
        al[e] = (__bf16)(av[e] - (float)hi);
    }
    bf16x8 bh0 = *(const bf16x8*)(bhb + k0);
    bf16x8 bh1 = *(const bf16x8*)(bhb + 16 * KPAD + k0);
    bf16x8 bh2 = *(const bf16x8*)(bhb + 32 * KPAD + k0);
    bf16x8 bh3 = *(const bf16x8*)(bhb + 48 * KPAD + k0);
    bf16x8 bl0 = *(const bf16x8*)(blb + k0);
    bf16x8 bl1 = *(const bf16x8*)(blb + 16 * KPAD + k0);
    bf16x8 bl2 = *(const bf16x8*)(blb + 32 * KPAD + k0);
    bf16x8 bl3 = *(const bf16x8*)(blb + 48 * KPAD + k0);
    a0 = __builtin_amdgcn_mfma_f32_16x16x32_bf16(ah, bh0, a0, 0, 0, 0);
    a1 = __builtin_amdgcn_mfma_f32_16x16x32_bf16(ah, bh1, a1, 0, 0, 0);
    a2 = __builtin_amdgcn_mfma_f32_16x16x32_bf16(ah, bh2, a2, 0, 0, 0);
    a3 = __builtin_amdgcn_mfma_f32_16x16x32_bf16(ah, bh3, a3, 0, 0, 0);
    a0 = __builtin_amdgcn_mfma_f32_16x16x32_bf16(al, bh0, a0, 0, 0, 0);
    a1 = __builtin_amdgcn_mfma_f32_16x16x32_bf16(al, bh1, a1, 0, 0, 0);
    a2 = __builtin_amdgcn_mfma_f32_16x16x32_bf16(al, bh2, a2, 0, 0, 0);
    a3 = __builtin_amdgcn_mfma_f32_16x16x32_bf16(al, bh3, a3, 0, 0, 0);
    a0 = __builtin_amdgcn_mfma_f32_16x16x32_bf16(ah, bl0, a0, 0, 0, 0);
    a1 = __builtin_amdgcn_mfma_f32_16x16x32_bf16(ah, bl1, a1, 0, 0, 0);
    a2 = __builtin_amdgcn_mfma_f32_16x16x32_bf16(ah, bl2, a2, 0, 0, 0);
    a3 = __builtin_amdgcn_mfma_f32_16x16x32_bf16(ah, bl3, a3, 0, 0, 0);
}

__global__ __launch_bounds__(256) void k_gemm1(const float* __restrict__ x,
    const __bf16* __restrict__ w1h, const __bf16* __restrict__ w1l,
    float* __restrict__ Hf, __bf16* __restrict__ Hb)
{
    const int w    = threadIdx.x >> 6;
    const int lane = threadIdx.x & 63;
    const int lr   = lane & 15;      // A-row within tile / B,C column within tile
    const int lk   = lane >> 4;      // k-block
    const int rbase = blockIdx.x * 64 + w * 16;
    int arow = rbase + lr; if (arow >= NN) arow = NN - 1;   // clamp (stores guarded)
    const float*  xk  = x   + (size_t)arow * FIN + lk * 8;
    const __bf16* bhb = w1h + (size_t)lr * KPAD + lk * 8;
    const __bf16* blb = w1l + (size_t)lr * KPAD + lk * 8;
    f32x4 a0 = {0,0,0,0}, a1 = {0,0,0,0}, a2 = {0,0,0,0}, a3 = {0,0,0,0};
    for (int kk = 0; kk < KFULL; ++kk)
        gemm1_step<false>(xk, kk * 32, lk, bhb, blb, a0, a1, a2, a3);
    gemm1_step<true>(xk, KFULL * 32, lk, bhb, blb, a0, a1, a2, a3);
    #pragma unroll
    for (int r = 0; r < 4; ++r){
        int row = rbase + lk * 4 + r;   // C/D: row = (lane>>4)*4 + reg, col = lane&15
        if (row < NN){
            float*  hf = Hf + (size_t)row * 64 + lr;
            __bf16* hb = Hb + (size_t)row * 64 + lr;
            hf[0]  = a0[r]; hf[16] = a1[r]; hf[32] = a2[r]; hf[48] = a3[r];
            hb[0]  = (__bf16)a0[r]; hb[16] = (__bf16)a1[r];
            hb[32] = (__bf16)a2[r]; hb[48] = (__bf16)a3[r];
        }
    }
}

// ---------------- attention logits, layer 1 ----------------
__global__ __launch_bounds__(256) void k_alpha1(const float* __restrict__ Hf,
    const float* __restrict__ a_s, const float* __restrict__ a_d,
    float* __restrict__ as1, float* __restrict__ ad1)
{
    __shared__ float sa[64], sd[64];
    int tid = threadIdx.x;
    if (tid < 64){ sa[tid] = a_s[tid]; sd[tid] = a_d[tid]; }
    __syncthreads();
    int n = blockIdx.x * 256 + tid;
    if (n >= NN) return;
    const float* hr = Hf + (size_t)n * 64;
    #pragma unroll
    for (int h = 0; h < 8; ++h){
        float s = 0.f, d = 0.f;
        #pragma unroll
        for (int c = 0; c < 8; ++c){
            float v = hr[h * 8 + c];
            s = fmaf(v, sa[h * 8 + c], s);
            d = fmaf(v, sd[h * 8 + c], d);
        }
        as1[n * 8 + h] = s;
        ad1[n * 8 + h] = d;
    }
}

// ---------------- layer-1 edge pass: one wave per dst node, lane = out channel ----------------
__global__ __launch_bounds__(256) void k_layer1(const float* __restrict__ as1, const float* __restrict__ ad1,
    const __bf16* __restrict__ Hb, const int* __restrict__ row_off, const int* __restrict__ csr,
    const float* __restrict__ b1, float* __restrict__ x2)
{
    int d    = blockIdx.x * 4 + (threadIdx.x >> 6);   // grid is exactly N/4 blocks
    int lane = threadIdx.x & 63;
    int h    = lane >> 3;
    float adv = ad1[d * 8 + h];
    float e0  = leaky02(as1[d * 8 + h] + adv);        // self loop
    float p0  = __expf(e0 - 20.f);                    // fixed-offset softmax (e bounded << 20)
    float den = p0;
    float acc = p0 * (float)Hb[(size_t)d * 64 + lane];
    int beg = row_off[d], end = row_off[d + 1];
    for (int base = beg; base < end; base += 8){
        int cnt = end - base; if (cnt > 8) cnt = 8;
        int li  = lane & 7;
        int si  = csr[base + (li < cnt ? li : cnt - 1)];
        float pas[8]; float ph[8];
        #pragma unroll
        for (int t = 0; t < 8; ++t){
            if (t < cnt){
                int s  = __shfl(si, t, 64);
                pas[t] = as1[s * 8 + h];
                ph[t]  = (float)Hb[(size_t)s * 64 + lane];
            }
        }
        #pragma unroll
        for (int t = 0; t < 8; ++t){
            if (t < cnt){
                float e = leaky02(pas[t] + adv);
                float p = __expf(e - 20.f);
                den += p;
                acc  = fmaf(p, ph[t], acc);
            }
        }
    }
    float o = acc / den + b1[lane];
    x2[(size_t)d * 64 + lane] = (o > 0.f) ? o : (__expf(o) - 1.f);   // ELU fused
}

// ---------------- GEMM2 + attention logits, layer 2 ----------------
__global__ __launch_bounds__(256) void k_gemm2(const float* __restrict__ x2, const float* __restrict__ W2,
    const float* __restrict__ aw_in, const float* __restrict__ dw_in,
    float* __restrict__ h2, float* __restrict__ as2, float* __restrict__ ad2)
{
    __shared__ float w2s[448];
    __shared__ float aw[7], dw[7];
    int tid = threadIdx.x;
    for (int i = tid; i < 448; i += 256) w2s[i] = W2[i];
    if (tid < 7){ aw[tid] = aw_in[tid]; dw[tid] = dw_in[tid]; }
    __syncthreads();
    int n = blockIdx.x * 256 + tid;
    if (n >= NN) return;
    const float4* xp = (const float4*)(x2 + (size_t)n * 64);
    float acc[7] = {0.f,0.f,0.f,0.f,0.f,0.f,0.f};
    #pragma unroll
    for (int q = 0; q < 16; ++q){
        float4 v = xp[q];
        float vv[4] = {v.x, v.y, v.z, v.w};
        #pragma unroll
        for (int u = 0; u < 4; ++u){
            int k = q * 4 + u;
            #pragma unroll
            for (int c = 0; c < 7; ++c) acc[c] = fmaf(vv[u], w2s[k * 7 + c], acc[c]);
        }
    }
    float s = 0.f, d = 0.f;
    #pragma unroll
    for (int c = 0; c < 7; ++c){ s = fmaf(acc[c], aw[c], s); d = fmaf(acc[c], dw[c], d); }
    float* hp = h2 + (size_t)n * 8;
    #pragma unroll
    for (int c = 0; c < 7; ++c) hp[c] = acc[c];
    hp[7] = 0.f;
    as2[n] = s; ad2[n] = d;
}

// ---------------- layer-2 edge pass + bias + log_softmax: 8 lanes per node ----------------
__global__ __launch_bounds__(256) void k_layer2(const float* __restrict__ as2, const float* __restrict__ ad2,
    const float* __restrict__ h2, const int* __restrict__ row_off, const int* __restrict__ csr,
    const float* __restrict__ b2, float* __restrict__ out)
{
    int tid  = threadIdx.x;
    int node = blockIdx.x * 32 + (tid >> 3);
    int c    = tid & 7;
    if (node >= NN) return;
    float adv = ad2[node];
    float e0  = leaky02(as2[node] + adv);
    float p0  = __expf(e0 - 20.f);
    float den = p0;
    float acc = p0 * h2[(size_t)node * 8 + c];        // c==7 reads the 0 pad
    int beg = row_off[node], end = row_off[node + 1];
    for (int i = beg; i < end; ++i){
        int s   = csr[i];
        float e = leaky02(as2[s] + adv);
        float p = __expf(e - 20.f);
        den += p;
        acc  = fmaf(p, h2[(size_t)s * 8 + c], acc);
    }
    float v = (c < 7) ? (acc / den + b2[c]) : -1e30f;
    float m = v;
    m = fmaxf(m, __shfl_xor(m, 1, 64));
    m = fmaxf(m, __shfl_xor(m, 2, 64));
    m = fmaxf(m, __shfl_xor(m, 4, 64));
    float ex = (c < 7) ? __expf(v - m) : 0.f;
    float s7 = ex;
    s7 += __shfl_xor(s7, 1, 64);
    s7 += __shfl_xor(s7, 2, 64);
    s7 += __shfl_xor(s7, 4, 64);
    if (c < 7) out[(size_t)node * 7 + c] = v - m - __logf(s7);
}

// ---------------- launcher ----------------
extern "C" void kernel_launch(void* const* d_in, const int* in_sizes, int n_in,
                              void* d_out, int out_size, void* d_ws, size_t ws_size,
                              hipStream_t stream)
{
    (void)n_in; (void)out_size; (void)ws_size;
    const float* x      = (const float*)d_in[0];
    const int*   ei     = (const int*)d_in[1];
    const int    E      = in_sizes[1] / 2;
    const float* W1     = (const float*)d_in[2];
    const float* asrc1  = (const float*)d_in[3];
    const float* adst1  = (const float*)d_in[4];
    const float* b1     = (const float*)d_in[5];
    const float* W2     = (const float*)d_in[6];
    const float* asrc2  = (const float*)d_in[7];
    const float* adst2  = (const float*)d_in[8];
    const float* b2     = (const float*)d_in[9];
    float* out = (float*)d_out;

    char* p = (char*)d_ws;
    auto alloc = [&](size_t bytes) -> void* {
        void* r = (void*)p;
        p += (bytes + 255) & ~(size_t)255;
        return r;
    };
    int*    deg     = (int*)alloc((size_t)NN * 4);
    int*    row_off = (int*)alloc((size_t)(NN + 1) * 4);
    int*    cursor  = (int*)alloc((size_t)NN * 4);
    int*    csr     = (int*)alloc((size_t)E * 4);
    __bf16* w1h     = (__bf16*)alloc((size_t)64 * KPAD * 2);
    __bf16* w1l     = (__bf16*)alloc((size_t)64 * KPAD * 2);
    float*  Hf      = (float*)alloc((size_t)NN * 64 * 4);
    __bf16* Hb      = (__bf16*)alloc((size_t)NN * 64 * 2);
    float*  as1     = (float*)alloc((size_t)NN * 8 * 4);
    float*  ad1     = (float*)alloc((size_t)NN * 8 * 4);
    float*  x2      = (float*)alloc((size_t)NN * 64 * 4);
    float*  h2      = (float*)alloc((size_t)NN * 8 * 4);
    float*  as2     = (float*)alloc((size_t)NN * 4);
    float*  ad2     = (float*)alloc((size_t)NN * 4);

    const int* src = ei;
    const int* dst = ei + E;

    hipMemsetAsync(deg, 0, (size_t)NN * 4, stream);
    k_hist   <<<(E + 255) / 256, 256, 0, stream>>>(dst, deg, E);
    k_scan   <<<1, 1024, 0, stream>>>(deg, row_off, cursor);
    k_scatter<<<(E + 255) / 256, 256, 0, stream>>>(src, dst, cursor, csr, E);
    k_w1t    <<<64, 256, 0, stream>>>(W1, w1h, w1l);
    k_gemm1  <<<(NN + 63) / 64, 256, 0, stream>>>(x, w1h, w1l, Hf, Hb);
    k_alpha1 <<<(NN + 255) / 256, 256, 0, stream>>>(Hf, asrc1, adst1, as1, ad1);
    k_layer1 <<<NN / 4, 256, 0, stream>>>(as1, ad1, Hb, row_off, csr, b1, x2);
    k_gemm2  <<<(NN + 255) / 256, 256, 0, stream>>>(x2, W2, asrc2, adst2, h2, as2, ad2);
    k_layer2 <<<(NN + 31) / 32, 256, 0, stream>>>(as2, ad2, h2, row_off, csr, b2, out);
}

// Round 2
// 680.613 us; speedup vs baseline: 1.0227x; 1.0227x over previous
//
#include <hip/hip_runtime.h>
#include <hip/hip_bf16.h>

static constexpr int NN    = 50000;
static constexpr int FIN   = 1433;
static constexpr int KPAD  = 1440;   // 45 * 32
static constexpr int NSTEP = 45;     // 45 k-steps of 32 (last one partially masked)

typedef __bf16 bf16x8 __attribute__((ext_vector_type(8)));
typedef float  f32x4  __attribute__((ext_vector_type(4)));

__device__ __forceinline__ float leaky02(float v){ return v >= 0.f ? v : 0.2f * v; }

// ---------------- CSR build ----------------
__global__ __launch_bounds__(256) void k_hist(const int* __restrict__ dst, int* __restrict__ deg, int E){
    int e = blockIdx.x * 256 + threadIdx.x;
    if (e < E) atomicAdd(&deg[dst[e]], 1);
}

__global__ __launch_bounds__(1024) void k_scan(const int* __restrict__ deg,
                                               int* __restrict__ row_off, int* __restrict__ cursor){
    __shared__ int sums[1024];
    const int PER = (NN + 1023) / 1024;   // 49
    int t = threadIdx.x;
    int base = t * PER;
    int local = 0;
    for (int i = 0; i < PER; ++i){ int idx = base + i; if (idx < NN) local += deg[idx]; }
    sums[t] = local;
    __syncthreads();
    for (int off = 1; off < 1024; off <<= 1){
        int v = sums[t];
        int add = (t >= off) ? sums[t - off] : 0;
        __syncthreads();
        sums[t] = v + add;
        __syncthreads();
    }
    int carry = (t > 0) ? sums[t - 1] : 0;
    for (int i = 0; i < PER; ++i){
        int idx = base + i;
        if (idx < NN){ row_off[idx] = carry; cursor[idx] = carry; carry += deg[idx]; }
    }
    if (t == 1023) row_off[NN] = carry;
}

__global__ __launch_bounds__(256) void k_scatter(const int* __restrict__ src, const int* __restrict__ dst,
                                                 int* __restrict__ cursor, int* __restrict__ csr, int E){
    int e = blockIdx.x * 256 + threadIdx.x;
    if (e < E){
        int d = dst[e];
        int pos = atomicAdd(&cursor[d], 1);
        csr[pos] = src[e];
    }
}

// ---------------- W1 transpose + bf16 split (hi/lo planes) ----------------
__global__ __launch_bounds__(256) void k_w1t(const float* __restrict__ W1,
                                             __bf16* __restrict__ w1h, __bf16* __restrict__ w1l){
    int c = blockIdx.x;                       // 0..63 output column
    for (int k = threadIdx.x; k < KPAD; k += 256){
        float v = (k < FIN) ? W1[(size_t)k * 64 + c] : 0.f;
        __bf16 hi = (__bf16)v;
        w1h[(size_t)c * KPAD + k] = hi;
        w1l[(size_t)c * KPAD + k] = (__bf16)(v - (float)hi);
    }
}

// ---------------- GEMM1: H = x @ W1 (split-bf16 MFMA, LDS-staged A, prefetched B) ----------------
__global__ __launch_bounds__(256) void k_gemm1(const float* __restrict__ x,
    const __bf16* __restrict__ w1h, const __bf16* __restrict__ w1l,
    float* __restrict__ Hf, __bf16* __restrict__ Hb)
{
    const int tid  = threadIdx.x;
    const int w    = tid >> 6;
    const int lane = tid & 63;
    const int lr   = lane & 15;      // A-row within 16-tile / B,C column within tile
    const int lk   = lane >> 4;      // k-block (8 elements each)
    const int rbase = blockIdx.x * 64;

    // staging role: thread t loads 8 consecutive k of row (t>>2), k-offset (t&3)*8
    const int srow  = tid >> 2;
    const int skoff = (tid & 3) * 8;
    int grow = rbase + srow; if (grow >= NN) grow = NN - 1;   // clamp; stores are guarded
    const float* xs = x + (size_t)grow * FIN;

    // B fragment pointers (L2-resident, 16B-aligned)
    const __bf16* bh_p = w1h + (size_t)lr * KPAD + lk * 8;
    const __bf16* bl_p = w1l + (size_t)lr * KPAD + lk * 8;

    // LDS A tiles: split hi/lo bf16, row stride 40 (80B) -> 2-way banks on ds_read_b128 (free)
    __shared__ __bf16 AH[2][64][40];
    __shared__ __bf16 AL[2][64][40];

    float av[8];
    #pragma unroll
    for (int e = 0; e < 8; ++e){
        int k = skoff + e;
        av[e] = (k < FIN) ? xs[k] : 0.f;
    }

    f32x4 a0 = {0,0,0,0}, a1 = {0,0,0,0}, a2 = {0,0,0,0}, a3 = {0,0,0,0};
    bf16x8 bh[4], bl[4];
    #pragma unroll
    for (int j = 0; j < 4; ++j){
        bh[j] = *(const bf16x8*)(bh_p + (size_t)j * 16 * KPAD);
        bl[j] = *(const bf16x8*)(bl_p + (size_t)j * 16 * KPAD);
    }

    {   // stage k-step 0 into buffer 0
        bf16x8 hv, lv;
        #pragma unroll
        for (int e = 0; e < 8; ++e){
            __bf16 h = (__bf16)av[e];
            hv[e] = h; lv[e] = (__bf16)(av[e] - (float)h);
        }
        *(bf16x8*)&AH[0][srow][skoff] = hv;
        *(bf16x8*)&AL[0][srow][skoff] = lv;
    }
    __syncthreads();

    #pragma unroll 2
    for (int kk = 0; kk < NSTEP; ++kk){
        const int  cur  = kk & 1;
        const bool more = (kk + 1 < NSTEP);
        float  avn[8];
        bf16x8 bhn[4], bln[4];
        if (more){
            const int k0n = (kk + 1) * 32;
            #pragma unroll
            for (int e = 0; e < 8; ++e){
                int k = k0n + skoff + e;
                avn[e] = (k < FIN) ? xs[k] : 0.f;
            }
            #pragma unroll
            for (int j = 0; j < 4; ++j){
                bhn[j] = *(const bf16x8*)(bh_p + (size_t)j * 16 * KPAD + k0n);
                bln[j] = *(const bf16x8*)(bl_p + (size_t)j * 16 * KPAD + k0n);
            }
        }
        // A fragments from LDS
        bf16x8 ah = *(const bf16x8*)&AH[cur][w * 16 + lr][lk * 8];
        bf16x8 al = *(const bf16x8*)&AL[cur][w * 16 + lr][lk * 8];
        // 12 MFMAs (hi*hi + lo*hi + hi*lo; drop lo*lo)
        a0 = __builtin_amdgcn_mfma_f32_16x16x32_bf16(ah, bh[0], a0, 0, 0, 0);
        a1 = __builtin_amdgcn_mfma_f32_16x16x32_bf16(ah, bh[1], a1, 0, 0, 0);
        a2 = __builtin_amdgcn_mfma_f32_16x16x32_bf16(ah, bh[2], a2, 0, 0, 0);
        a3 = __builtin_amdgcn_mfma_f32_16x16x32_bf16(ah, bh[3], a3, 0, 0, 0);
        a0 = __builtin_amdgcn_mfma_f32_16x16x32_bf16(al, bh[0], a0, 0, 0, 0);
        a1 = __builtin_amdgcn_mfma_f32_16x16x32_bf16(al, bh[1], a1, 0, 0, 0);
        a2 = __builtin_amdgcn_mfma_f32_16x16x32_bf16(al, bh[2], a2, 0, 0, 0);
        a3 = __builtin_amdgcn_mfma_f32_16x16x32_bf16(al, bh[3], a3, 0, 0, 0);
        a0 = __builtin_amdgcn_mfma_f32_16x16x32_bf16(ah, bl[0], a0, 0, 0, 0);
        a1 = __builtin_amdgcn_mfma_f32_16x16x32_bf16(ah, bl[1], a1, 0, 0, 0);
        a2 = __builtin_amdgcn_mfma_f32_16x16x32_bf16(ah, bl[2], a2, 0, 0, 0);
        a3 = __builtin_amdgcn_mfma_f32_16x16x32_bf16(ah, bl[3], a3, 0, 0, 0);
        if (more){
            bf16x8 hv, lv;
            #pragma unroll
            for (int e = 0; e < 8; ++e){
                __bf16 h = (__bf16)avn[e];
                hv[e] = h; lv[e] = (__bf16)(avn[e] - (float)h);
            }
            *(bf16x8*)&AH[1 - cur][srow][skoff] = hv;
            *(bf16x8*)&AL[1 - cur][srow][skoff] = lv;
            #pragma unroll
            for (int j = 0; j < 4; ++j){ bh[j] = bhn[j]; bl[j] = bln[j]; }
        }
        __syncthreads();
    }

    #pragma unroll
    for (int r = 0; r < 4; ++r){
        int row = rbase + w * 16 + lk * 4 + r;   // C/D: row = (lane>>4)*4 + reg, col = lane&15
        if (row < NN){
            float*  hf = Hf + (size_t)row * 64 + lr;
            __bf16* hb = Hb + (size_t)row * 64 + lr;
            hf[0]  = a0[r]; hf[16] = a1[r]; hf[32] = a2[r]; hf[48] = a3[r];
            hb[0]  = (__bf16)a0[r]; hb[16] = (__bf16)a1[r];
            hb[32] = (__bf16)a2[r]; hb[48] = (__bf16)a3[r];
        }
    }
}

// ---------------- attention logits, layer 1 ----------------
__global__ __launch_bounds__(256) void k_alpha1(const float* __restrict__ Hf,
    const float* __restrict__ a_s, const float* __restrict__ a_d,
    float* __restrict__ as1, float* __restrict__ ad1)
{
    __shared__ float sa[64], sd[64];
    int tid = threadIdx.x;
    if (tid < 64){ sa[tid] = a_s[tid]; sd[tid] = a_d[tid]; }
    __syncthreads();
    int n = blockIdx.x * 256 + tid;
    if (n >= NN) return;
    const float* hr = Hf + (size_t)n * 64;
    #pragma unroll
    for (int h = 0; h < 8; ++h){
        float s = 0.f, d = 0.f;
        #pragma unroll
        for (int c = 0; c < 8; ++c){
            float v = hr[h * 8 + c];
            s = fmaf(v, sa[h * 8 + c], s);
            d = fmaf(v, sd[h * 8 + c], d);
        }
        as1[n * 8 + h] = s;
        ad1[n * 8 + h] = d;
    }
}

// ---------------- layer-1 edge pass: one wave per dst node, lane = out channel ----------------
__global__ __launch_bounds__(256) void k_layer1(const float* __restrict__ as1, const float* __restrict__ ad1,
    const __bf16* __restrict__ Hb, const int* __restrict__ row_off, const int* __restrict__ csr,
    const float* __restrict__ b1, float* __restrict__ x2)
{
    int d    = blockIdx.x * 4 + (threadIdx.x >> 6);   // grid is exactly N/4 blocks
    int lane = threadIdx.x & 63;
    int h    = lane >> 3;
    float adv = ad1[d * 8 + h];
    float e0  = leaky02(as1[d * 8 + h] + adv);        // self loop
    float p0  = __expf(e0 - 20.f);                    // fixed-offset softmax (e bounded << 20)
    float den = p0;
    float acc = p0 * (float)Hb[(size_t)d * 64 + lane];
    int beg = row_off[d], end = row_off[d + 1];
    for (int base = beg; base < end; base += 8){
        int cnt = end - base; if (cnt > 8) cnt = 8;
        int li  = lane & 7;
        int si  = csr[base + (li < cnt ? li : cnt - 1)];
        float pas[8]; float ph[8];
        #pragma unroll
        for (int t = 0; t < 8; ++t){
            if (t < cnt){
                int s  = __shfl(si, t, 64);
                pas[t] = as1[s * 8 + h];
                ph[t]  = (float)Hb[(size_t)s * 64 + lane];
            }
        }
        #pragma unroll
        for (int t = 0; t < 8; ++t){
            if (t < cnt){
                float e = leaky02(pas[t] + adv);
                float p = __expf(e - 20.f);
                den += p;
                acc  = fmaf(p, ph[t], acc);
            }
        }
    }
    float o = acc / den + b1[lane];
    x2[(size_t)d * 64 + lane] = (o > 0.f) ? o : (__expf(o) - 1.f);   // ELU fused
}

// ---------------- GEMM2 + attention logits, layer 2 ----------------
__global__ __launch_bounds__(256) void k_gemm2(const float* __restrict__ x2, const float* __restrict__ W2,
    const float* __restrict__ aw_in, const float* __restrict__ dw_in,
    float* __restrict__ h2, float* __restrict__ as2, float* __restrict__ ad2)
{
    __shared__ float w2s[448];
    __shared__ float aw[7], dw[7];
    int tid = threadIdx.x;
    for (int i = tid; i < 448; i += 256) w2s[i] = W2[i];
    if (tid < 7){ aw[tid] = aw_in[tid]; dw[tid] = dw_in[tid]; }
    __syncthreads();
    int n = blockIdx.x * 256 + tid;
    if (n >= NN) return;
    const float4* xp = (const float4*)(x2 + (size_t)n * 64);
    float acc[7] = {0.f,0.f,0.f,0.f,0.f,0.f,0.f};
    #pragma unroll
    for (int q = 0; q < 16; ++q){
        float4 v = xp[q];
        float vv[4] = {v.x, v.y, v.z, v.w};
        #pragma unroll
        for (int u = 0; u < 4; ++u){
            int k = q * 4 + u;
            #pragma unroll
            for (int c = 0; c < 7; ++c) acc[c] = fmaf(vv[u], w2s[k * 7 + c], acc[c]);
        }
    }
    float s = 0.f, d = 0.f;
    #pragma unroll
    for (int c = 0; c < 7; ++c){ s = fmaf(acc[c], aw[c], s); d = fmaf(acc[c], dw[c], d); }
    float* hp = h2 + (size_t)n * 8;
    #pragma unroll
    for (int c = 0; c < 7; ++c) hp[c] = acc[c];
    hp[7] = 0.f;
    as2[n] = s; ad2[n] = d;
}

// ---------------- layer-2 edge pass + bias + log_softmax: 8 lanes per node ----------------
__global__ __launch_bounds__(256) void k_layer2(const float* __restrict__ as2, const float* __restrict__ ad2,
    const float* __restrict__ h2, const int* __restrict__ row_off, const int* __restrict__ csr,
    const float* __restrict__ b2, float* __restrict__ out)
{
    int tid  = threadIdx.x;
    int node = blockIdx.x * 32 + (tid >> 3);
    int c    = tid & 7;
    if (node >= NN) return;
    float adv = ad2[node];
    float e0  = leaky02(as2[node] + adv);
    float p0  = __expf(e0 - 20.f);
    float den = p0;
    float acc = p0 * h2[(size_t)node * 8 + c];        // c==7 reads the 0 pad
    int beg = row_off[node], end = row_off[node + 1];
    for (int i = beg; i < end; ++i){
        int s   = csr[i];
        float e = leaky02(as2[s] + adv);
        float p = __expf(e - 20.f);
        den += p;
        acc  = fmaf(p, h2[(size_t)s * 8 + c], acc);
    }
    float v = (c < 7) ? (acc / den + b2[c]) : -1e30f;
    float m = v;
    m = fmaxf(m, __shfl_xor(m, 1, 64));
    m = fmaxf(m, __shfl_xor(m, 2, 64));
    m = fmaxf(m, __shfl_xor(m, 4, 64));
    float ex = (c < 7) ? __expf(v - m) : 0.f;
    float s7 = ex;
    s7 += __shfl_xor(s7, 1, 64);
    s7 += __shfl_xor(s7, 2, 64);
    s7 += __shfl_xor(s7, 4, 64);
    if (c < 7) out[(size_t)node * 7 + c] = v - m - __logf(s7);
}

// ---------------- launcher ----------------
extern "C" void kernel_launch(void* const* d_in, const int* in_sizes, int n_in,
                              void* d_out, int out_size, void* d_ws, size_t ws_size,
                              hipStream_t stream)
{
    (void)n_in; (void)out_size; (void)ws_size;
    const float* x      = (const float*)d_in[0];
    const int*   ei     = (const int*)d_in[1];
    const int    E      = in_sizes[1] / 2;
    const float* W1     = (const float*)d_in[2];
    const float* asrc1  = (const float*)d_in[3];
    const float* adst1  = (const float*)d_in[4];
    const float* b1     = (const float*)d_in[5];
    const float* W2     = (const float*)d_in[6];
    const float* asrc2  = (const float*)d_in[7];
    const float* adst2  = (const float*)d_in[8];
    const float* b2     = (const float*)d_in[9];
    float* out = (float*)d_out;

    char* p = (char*)d_ws;
    auto alloc = [&](size_t bytes) -> void* {
        void* r = (void*)p;
        p += (bytes + 255) & ~(size_t)255;
        return r;
    };
    int*    deg     = (int*)alloc((size_t)NN * 4);
    int*    row_off = (int*)alloc((size_t)(NN + 1) * 4);
    int*    cursor  = (int*)alloc((size_t)NN * 4);
    int*    csr     = (int*)alloc((size_t)E * 4);
    __bf16* w1h     = (__bf16*)alloc((size_t)64 * KPAD * 2);
    __bf16* w1l     = (__bf16*)alloc((size_t)64 * KPAD * 2);
    float*  Hf      = (float*)alloc((size_t)NN * 64 * 4);
    __bf16* Hb      = (__bf16*)alloc((size_t)NN * 64 * 2);
    float*  as1     = (float*)alloc((size_t)NN * 8 * 4);
    float*  ad1     = (float*)alloc((size_t)NN * 8 * 4);
    float*  x2      = (float*)alloc((size_t)NN * 64 * 4);
    float*  h2      = (float*)alloc((size_t)NN * 8 * 4);
    float*  as2     = (float*)alloc((size_t)NN * 4);
    float*  ad2     = (float*)alloc((size_t)NN * 4);

    const int* src = ei;
    const int* dst = ei + E;

    hipMemsetAsync(deg, 0, (size_t)NN * 4, stream);
    k_hist   <<<(E + 255) / 256, 256, 0, stream>>>(dst, deg, E);
    k_scan   <<<1, 1024, 0, stream>>>(deg, row_off, cursor);
    k_scatter<<<(E + 255) / 256, 256, 0, stream>>>(src, dst, cursor, csr, E);
    k_w1t    <<<64, 256, 0, stream>>>(W1, w1h, w1l);
    k_gemm1  <<<(NN + 63) / 64, 256, 0, stream>>>(x, w1h, w1l, Hf, Hb);
    k_alpha1 <<<(NN + 255) / 256, 256, 0, stream>>>(Hf, asrc1, adst1, as1, ad1);
    k_layer1 <<<NN / 4, 256, 0, stream>>>(as1, ad1, Hb, row_off, csr, b1, x2);
    k_gemm2  <<<(NN + 255) / 256, 256, 0, stream>>>(x2, W2, asrc2, adst2, h2, as2, ad2);
    k_layer2 <<<(NN + 31) / 32, 256, 0, stream>>>(as2, ad2, h2, row_off, csr, b2, out);
}

// Round 3
// 668.255 us; speedup vs baseline: 1.0416x; 1.0185x over previous
//
#include <hip/hip_runtime.h>
#include <hip/hip_bf16.h>

static constexpr int NN    = 50000;
static constexpr int FIN   = 1433;
static constexpr int KPAD  = 1440;   // 45 * 32

typedef __bf16 bf16x8 __attribute__((ext_vector_type(8)));
typedef float  f32x4  __attribute__((ext_vector_type(4)));

__device__ __forceinline__ float leaky02(float v){ return v >= 0.f ? v : 0.2f * v; }

// ---------------- CSR build ----------------
__global__ __launch_bounds__(256) void k_hist(const int* __restrict__ dst, int* __restrict__ deg, int E){
    int e = blockIdx.x * 256 + threadIdx.x;
    if (e < E) atomicAdd(&deg[dst[e]], 1);
}

__global__ __launch_bounds__(1024) void k_scan(const int* __restrict__ deg,
                                               int* __restrict__ row_off, int* __restrict__ cursor){
    __shared__ int sums[1024];
    const int PER = (NN + 1023) / 1024;   // 49
    int t = threadIdx.x;
    int base = t * PER;
    int local = 0;
    for (int i = 0; i < PER; ++i){ int idx = base + i; if (idx < NN) local += deg[idx]; }
    sums[t] = local;
    __syncthreads();
    for (int off = 1; off < 1024; off <<= 1){
        int v = sums[t];
        int add = (t >= off) ? sums[t - off] : 0;
        __syncthreads();
        sums[t] = v + add;
        __syncthreads();
    }
    int carry = (t > 0) ? sums[t - 1] : 0;
    for (int i = 0; i < PER; ++i){
        int idx = base + i;
        if (idx < NN){ row_off[idx] = carry; cursor[idx] = carry; carry += deg[idx]; }
    }
    if (t == 1023) row_off[NN] = carry;
}

__global__ __launch_bounds__(256) void k_scatter(const int* __restrict__ src, const int* __restrict__ dst,
                                                 int* __restrict__ cursor, int* __restrict__ csr, int E){
    int e = blockIdx.x * 256 + threadIdx.x;
    if (e < E){
        int d = dst[e];
        int pos = atomicAdd(&cursor[d], 1);
        csr[pos] = src[e];
    }
}

// ---------------- W1 transpose + bf16 split (hi/lo planes) ----------------
__global__ __launch_bounds__(256) void k_w1t(const float* __restrict__ W1,
                                             __bf16* __restrict__ w1h, __bf16* __restrict__ w1l){
    int c = blockIdx.x;                       // 0..63 output column
    for (int k = threadIdx.x; k < KPAD; k += 256){
        float v = (k < FIN) ? W1[(size_t)k * 64 + c] : 0.f;
        __bf16 hi = (__bf16)v;
        w1h[(size_t)c * KPAD + k] = hi;
        w1l[(size_t)c * KPAD + k] = (__bf16)(v - (float)hi);
    }
}

// ---------------- GEMM1 inner chunk: guard-free, 1-deep register pipeline ----------------
#define MFMA12(AH, AL, BH, BL)                                                   \
    acc[0] = __builtin_amdgcn_mfma_f32_16x16x32_bf16(AH, BH[0], acc[0], 0,0,0);  \
    acc[1] = __builtin_amdgcn_mfma_f32_16x16x32_bf16(AH, BH[1], acc[1], 0,0,0);  \
    acc[2] = __builtin_amdgcn_mfma_f32_16x16x32_bf16(AH, BH[2], acc[2], 0,0,0);  \
    acc[3] = __builtin_amdgcn_mfma_f32_16x16x32_bf16(AH, BH[3], acc[3], 0,0,0);  \
    acc[0] = __builtin_amdgcn_mfma_f32_16x16x32_bf16(AL, BH[0], acc[0], 0,0,0);  \
    acc[1] = __builtin_amdgcn_mfma_f32_16x16x32_bf16(AL, BH[1], acc[1], 0,0,0);  \
    acc[2] = __builtin_amdgcn_mfma_f32_16x16x32_bf16(AL, BH[2], acc[2], 0,0,0);  \
    acc[3] = __builtin_amdgcn_mfma_f32_16x16x32_bf16(AL, BH[3], acc[3], 0,0,0);  \
    acc[0] = __builtin_amdgcn_mfma_f32_16x16x32_bf16(AH, BL[0], acc[0], 0,0,0);  \
    acc[1] = __builtin_amdgcn_mfma_f32_16x16x32_bf16(AH, BL[1], acc[1], 0,0,0);  \
    acc[2] = __builtin_amdgcn_mfma_f32_16x16x32_bf16(AH, BL[2], acc[2], 0,0,0);  \
    acc[3] = __builtin_amdgcn_mfma_f32_16x16x32_bf16(AH, BL[3], acc[3], 0,0,0);

template<int KS, int KE>
__device__ __forceinline__ void gemm1_chunk(const float* __restrict__ xk,
    const __bf16* __restrict__ bh_p, const __bf16* __restrict__ bl_p, f32x4* acc)
{
    float ac[8]; bf16x8 bhc[4], blc[4];
    #pragma unroll
    for (int e = 0; e < 8; ++e) ac[e] = xk[KS * 32 + e];
    #pragma unroll
    for (int j = 0; j < 4; ++j){
        bhc[j] = *(const bf16x8*)(bh_p + (size_t)j * 16 * KPAD + KS * 32);
        blc[j] = *(const bf16x8*)(bl_p + (size_t)j * 16 * KPAD + KS * 32);
    }
    #pragma unroll 2
    for (int kk = KS; kk < KE; ++kk){
        float an[8]; bf16x8 bhn[4], bln[4];
        const bool more = (kk + 1 < KE);
        if (more){
            #pragma unroll
            for (int e = 0; e < 8; ++e) an[e] = xk[(kk + 1) * 32 + e];
            #pragma unroll
            for (int j = 0; j < 4; ++j){
                bhn[j] = *(const bf16x8*)(bh_p + (size_t)j * 16 * KPAD + (kk + 1) * 32);
                bln[j] = *(const bf16x8*)(bl_p + (size_t)j * 16 * KPAD + (kk + 1) * 32);
            }
        }
        bf16x8 ah, al;
        #pragma unroll
        for (int e = 0; e < 8; ++e){
            __bf16 h = (__bf16)ac[e];
            ah[e] = h; al[e] = (__bf16)(ac[e] - (float)h);
        }
        MFMA12(ah, al, bhc, blc)
        if (more){
            #pragma unroll
            for (int e = 0; e < 8; ++e) ac[e] = an[e];
            #pragma unroll
            for (int j = 0; j < 4; ++j){ bhc[j] = bhn[j]; blc[j] = bln[j]; }
        }
    }
}

// GEMM1: 4 waves/block; waves {0,1}=K-chunk0 rows{0-15,16-31}, waves {2,3}=K-chunk1.
// No barrier in the K loop; partials combined via LDS once at the end.
__global__ __launch_bounds__(256, 4) void k_gemm1(const float* __restrict__ x,
    const __bf16* __restrict__ w1h, const __bf16* __restrict__ w1l,
    float* __restrict__ Hf, __bf16* __restrict__ Hb)
{
    const int tid  = threadIdx.x;
    const int w    = tid >> 6;
    const int lane = tid & 63;
    const int lr   = lane & 15;      // A-row within 16-tile / B,C column within tile
    const int lk   = lane >> 4;      // k-block (8 elements)
    const int quad = w & 1;          // row group
    const int half = w >> 1;         // K chunk
    const int rbase = blockIdx.x * 32 + quad * 16;
    int arow = rbase + lr; if (arow >= NN) arow = NN - 1;   // clamp; stores guarded
    const float*  xk   = x   + (size_t)arow * FIN + lk * 8;
    const __bf16* bh_p = w1h + (size_t)lr * KPAD + lk * 8;
    const __bf16* bl_p = w1l + (size_t)lr * KPAD + lk * 8;

    f32x4 acc[4] = {{0,0,0,0},{0,0,0,0},{0,0,0,0},{0,0,0,0}};

    if (half == 0){
        gemm1_chunk<0, 22>(xk, bh_p, bl_p, acc);
    } else {
        gemm1_chunk<22, 44>(xk, bh_p, bl_p, acc);
        // peeled masked tail: k-step 44 covers k 1408..1439, FIN=1433
        float at[8];
        #pragma unroll
        for (int e = 0; e < 8; ++e){
            int k = 1408 + lk * 8 + e;
            at[e] = (k < FIN) ? xk[44 * 32 + e] : 0.f;
        }
        bf16x8 bht[4], blt[4];
        #pragma unroll
        for (int j = 0; j < 4; ++j){
            bht[j] = *(const bf16x8*)(bh_p + (size_t)j * 16 * KPAD + 1408);
            blt[j] = *(const bf16x8*)(bl_p + (size_t)j * 16 * KPAD + 1408);
        }
        bf16x8 ah, al;
        #pragma unroll
        for (int e = 0; e < 8; ++e){
            __bf16 h = (__bf16)at[e];
            ah[e] = h; al[e] = (__bf16)(at[e] - (float)h);
        }
        MFMA12(ah, al, bht, blt)
    }

    __shared__ float Hs[32][66];
    if (half == 1){
        #pragma unroll
        for (int j = 0; j < 4; ++j)
            #pragma unroll
            for (int r = 0; r < 4; ++r)
                Hs[quad * 16 + lk * 4 + r][lr + 16 * j] = acc[j][r];
    }
    __syncthreads();
    if (half == 0){
        #pragma unroll
        for (int r = 0; r < 4; ++r){
            int rib = quad * 16 + lk * 4 + r;
            int row = blockIdx.x * 32 + rib;
            if (row < NN){
                float v0 = acc[0][r] + Hs[rib][lr];
                float v1 = acc[1][r] + Hs[rib][lr + 16];
                float v2 = acc[2][r] + Hs[rib][lr + 32];
                float v3 = acc[3][r] + Hs[rib][lr + 48];
                float*  hf = Hf + (size_t)row * 64 + lr;
                __bf16* hb = Hb + (size_t)row * 64 + lr;
                hf[0] = v0; hf[16] = v1; hf[32] = v2; hf[48] = v3;
                hb[0] = (__bf16)v0; hb[16] = (__bf16)v1;
                hb[32] = (__bf16)v2; hb[48] = (__bf16)v3;
            }
        }
    }
}

// ---------------- attention logits, layer 1 ----------------
__global__ __launch_bounds__(256) void k_alpha1(const float* __restrict__ Hf,
    const float* __restrict__ a_s, const float* __restrict__ a_d,
    float* __restrict__ as1, float* __restrict__ ad1)
{
    __shared__ float sa[64], sd[64];
    int tid = threadIdx.x;
    if (tid < 64){ sa[tid] = a_s[tid]; sd[tid] = a_d[tid]; }
    __syncthreads();
    int n = blockIdx.x * 256 + tid;
    if (n >= NN) return;
    const float* hr = Hf + (size_t)n * 64;
    #pragma unroll
    for (int h = 0; h < 8; ++h){
        float s = 0.f, d = 0.f;
        #pragma unroll
        for (int c = 0; c < 8; ++c){
            float v = hr[h * 8 + c];
            s = fmaf(v, sa[h * 8 + c], s);
            d = fmaf(v, sd[h * 8 + c], d);
        }
        as1[n * 8 + h] = s;
        ad1[n * 8 + h] = d;
    }
}

// ---------------- layer-1 edge pass: one wave per dst node, lane = out channel ----------------
__global__ __launch_bounds__(256) void k_layer1(const float* __restrict__ as1, const float* __restrict__ ad1,
    const __bf16* __restrict__ Hb, const int* __restrict__ row_off, const int* __restrict__ csr,
    const float* __restrict__ b1, float* __restrict__ x2)
{
    int d    = blockIdx.x * 4 + (threadIdx.x >> 6);   // grid is exactly N/4 blocks
    int lane = threadIdx.x & 63;
    int h    = lane >> 3;
    float adv = ad1[d * 8 + h];
    float e0  = leaky02(as1[d * 8 + h] + adv);        // self loop
    float p0  = __expf(e0 - 20.f);                    // fixed-offset softmax (e bounded << 20)
    float den = p0;
    float acc = p0 * (float)Hb[(size_t)d * 64 + lane];
    int beg = row_off[d], end = row_off[d + 1];
    for (int base = beg; base < end; base += 8){
        int cnt = end - base; if (cnt > 8) cnt = 8;
        int li  = lane & 7;
        int si  = csr[base + (li < cnt ? li : cnt - 1)];
        float pas[8]; float ph[8];
        #pragma unroll
        for (int t = 0; t < 8; ++t){
            if (t < cnt){
                int s  = __shfl(si, t, 64);
                pas[t] = as1[s * 8 + h];
                ph[t]  = (float)Hb[(size_t)s * 64 + lane];
            }
        }
        #pragma unroll
        for (int t = 0; t < 8; ++t){
            if (t < cnt){
                float e = leaky02(pas[t] + adv);
                float p = __expf(e - 20.f);
                den += p;
                acc  = fmaf(p, ph[t], acc);
            }
        }
    }
    float o = acc / den + b1[lane];
    x2[(size_t)d * 64 + lane] = (o > 0.f) ? o : (__expf(o) - 1.f);   // ELU fused
}

// ---------------- GEMM2 + attention logits, layer 2 ----------------
__global__ __launch_bounds__(256) void k_gemm2(const float* __restrict__ x2, const float* __restrict__ W2,
    const float* __restrict__ aw_in, const float* __restrict__ dw_in,
    float* __restrict__ h2, float* __restrict__ as2, float* __restrict__ ad2)
{
    __shared__ float w2s[448];
    __shared__ float aw[7], dw[7];
    int tid = threadIdx.x;
    for (int i = tid; i < 448; i += 256) w2s[i] = W2[i];
    if (tid < 7){ aw[tid] = aw_in[tid]; dw[tid] = dw_in[tid]; }
    __syncthreads();
    int n = blockIdx.x * 256 + tid;
    if (n >= NN) return;
    const float4* xp = (const float4*)(x2 + (size_t)n * 64);
    float acc[7] = {0.f,0.f,0.f,0.f,0.f,0.f,0.f};
    #pragma unroll
    for (int q = 0; q < 16; ++q){
        float4 v = xp[q];
        float vv[4] = {v.x, v.y, v.z, v.w};
        #pragma unroll
        for (int u = 0; u < 4; ++u){
            int k = q * 4 + u;
            #pragma unroll
            for (int c = 0; c < 7; ++c) acc[c] = fmaf(vv[u], w2s[k * 7 + c], acc[c]);
        }
    }
    float s = 0.f, d = 0.f;
    #pragma unroll
    for (int c = 0; c < 7; ++c){ s = fmaf(acc[c], aw[c], s); d = fmaf(acc[c], dw[c], d); }
    float* hp = h2 + (size_t)n * 8;
    #pragma unroll
    for (int c = 0; c < 7; ++c) hp[c] = acc[c];
    hp[7] = 0.f;
    as2[n] = s; ad2[n] = d;
}

// ---------------- layer-2 edge pass + bias + log_softmax: 8 lanes per node, 8-edge batches ----------------
__global__ __launch_bounds__(256) void k_layer2(const float* __restrict__ as2, const float* __restrict__ ad2,
    const float* __restrict__ h2, const int* __restrict__ row_off, const int* __restrict__ csr,
    const float* __restrict__ b2, float* __restrict__ out)
{
    int tid  = threadIdx.x;
    int node = blockIdx.x * 32 + (tid >> 3);
    int c    = tid & 7;
    if (node >= NN) return;
    float adv = ad2[node];
    float e0  = leaky02(as2[node] + adv);
    float p0  = __expf(e0 - 20.f);
    float den = p0;
    float acc = p0 * h2[(size_t)node * 8 + c];        // c==7 reads the 0 pad
    int beg = row_off[node], end = row_off[node + 1];
    for (int base = beg; base < end; base += 8){
        int cnt = end - base; if (cnt > 8) cnt = 8;
        int si  = csr[base + (c < cnt ? c : cnt - 1)];
        float pa[8]; float ph[8];
        #pragma unroll
        for (int t = 0; t < 8; ++t){
            if (t < cnt){
                int s = __shfl(si, t, 8);             // lane (group*8 + t)
                pa[t] = as2[s];
                ph[t] = h2[(size_t)s * 8 + c];
            }
        }
        #pragma unroll
        for (int t = 0; t < 8; ++t){
            if (t < cnt){
                float e = leaky02(pa[t] + adv);
                float p = __expf(e - 20.f);
                den += p;
                acc  = fmaf(p, ph[t], acc);
            }
        }
    }
    float v = (c < 7) ? (acc / den + b2[c]) : -1e30f;
    float m = v;
    m = fmaxf(m, __shfl_xor(m, 1, 64));
    m = fmaxf(m, __shfl_xor(m, 2, 64));
    m = fmaxf(m, __shfl_xor(m, 4, 64));
    float ex = (c < 7) ? __expf(v - m) : 0.f;
    float s7 = ex;
    s7 += __shfl_xor(s7, 1, 64);
    s7 += __shfl_xor(s7, 2, 64);
    s7 += __shfl_xor(s7, 4, 64);
    if (c < 7) out[(size_t)node * 7 + c] = v - m - __logf(s7);
}

// ---------------- launcher ----------------
extern "C" void kernel_launch(void* const* d_in, const int* in_sizes, int n_in,
                              void* d_out, int out_size, void* d_ws, size_t ws_size,
                              hipStream_t stream)
{
    (void)n_in; (void)out_size; (void)ws_size;
    const float* x      = (const float*)d_in[0];
    const int*   ei     = (const int*)d_in[1];
    const int    E      = in_sizes[1] / 2;
    const float* W1     = (const float*)d_in[2];
    const float* asrc1  = (const float*)d_in[3];
    const float* adst1  = (const float*)d_in[4];
    const float* b1     = (const float*)d_in[5];
    const float* W2     = (const float*)d_in[6];
    const float* asrc2  = (const float*)d_in[7];
    const float* adst2  = (const float*)d_in[8];
    const float* b2     = (const float*)d_in[9];
    float* out = (float*)d_out;

    char* p = (char*)d_ws;
    auto alloc = [&](size_t bytes) -> void* {
        void* r = (void*)p;
        p += (bytes + 255) & ~(size_t)255;
        return r;
    };
    int*    deg     = (int*)alloc((size_t)NN * 4);
    int*    row_off = (int*)alloc((size_t)(NN + 1) * 4);
    int*    cursor  = (int*)alloc((size_t)NN * 4);
    int*    csr     = (int*)alloc((size_t)E * 4);
    __bf16* w1h     = (__bf16*)alloc((size_t)64 * KPAD * 2);
    __bf16* w1l     = (__bf16*)alloc((size_t)64 * KPAD * 2);
    float*  Hf      = (float*)alloc((size_t)NN * 64 * 4);
    __bf16* Hb      = (__bf16*)alloc((size_t)NN * 64 * 2);
    float*  as1     = (float*)alloc((size_t)NN * 8 * 4);
    float*  ad1     = (float*)alloc((size_t)NN * 8 * 4);
    float*  x2      = (float*)alloc((size_t)NN * 64 * 4);
    float*  h2      = (float*)alloc((size_t)NN * 8 * 4);
    float*  as2     = (float*)alloc((size_t)NN * 4);
    float*  ad2     = (float*)alloc((size_t)NN * 4);

    const int* src = ei;
    const int* dst = ei + E;

    hipMemsetAsync(deg, 0, (size_t)NN * 4, stream);
    k_hist   <<<(E + 255) / 256, 256, 0, stream>>>(dst, deg, E);
    k_scan   <<<1, 1024, 0, stream>>>(deg, row_off, cursor);
    k_scatter<<<(E + 255) / 256, 256, 0, stream>>>(src, dst, cursor, csr, E);
    k_w1t    <<<64, 256, 0, stream>>>(W1, w1h, w1l);
    k_gemm1  <<<(NN + 31) / 32, 256, 0, stream>>>(x, w1h, w1l, Hf, Hb);
    k_alpha1 <<<(NN + 255) / 256, 256, 0, stream>>>(Hf, asrc1, adst1, as1, ad1);
    k_layer1 <<<NN / 4, 256, 0, stream>>>(as1, ad1, Hb, row_off, csr, b1, x2);
    k_gemm2  <<<(NN + 255) / 256, 256, 0, stream>>>(x2, W2, asrc2, adst2, h2, as2, ad2);
    k_layer2 <<<(NN + 31) / 32, 256, 0, stream>>>(as2, ad2, h2, row_off, csr, b2, out);
}

// Round 4
// 457.529 us; speedup vs baseline: 1.5214x; 1.4606x over previous
//
#include <hip/hip_runtime.h>
#include <hip/hip_bf16.h>

static constexpr int NN      = 50000;
static constexpr int FIN     = 1433;
static constexpr int KPAD    = 1440;            // 45 * 32
static constexpr int NB_SCAN = (NN + 255) / 256; // 196

typedef __bf16 bf16x8 __attribute__((ext_vector_type(8)));
typedef float  f32x4  __attribute__((ext_vector_type(4)));

__device__ __forceinline__ float leaky02(float v){ return v >= 0.f ? v : 0.2f * v; }

// async global->LDS, 4 bytes/lane: lane l writes lds_base + l*4
__device__ __forceinline__ void gld_lds4(const float* g, float* l){
    __builtin_amdgcn_global_load_lds(
        (const __attribute__((address_space(1))) unsigned int*)g,
        (__attribute__((address_space(3))) unsigned int*)l, 4, 0, 0);
}

// ---------------- CSR build ----------------
__global__ __launch_bounds__(256) void k_hist(const int* __restrict__ dst, int* __restrict__ deg, int E){
    int e = blockIdx.x * 256 + threadIdx.x;
    if (e < E) atomicAdd(&deg[dst[e]], 1);
}

__global__ __launch_bounds__(256) void k_scan1(const int* __restrict__ deg, int* __restrict__ bsum){
    __shared__ int red[256];
    int i = blockIdx.x * 256 + threadIdx.x;
    red[threadIdx.x] = (i < NN) ? deg[i] : 0;
    __syncthreads();
    for (int off = 128; off > 0; off >>= 1){
        if (threadIdx.x < off) red[threadIdx.x] += red[threadIdx.x + off];
        __syncthreads();
    }
    if (threadIdx.x == 0) bsum[blockIdx.x] = red[0];
}

__global__ __launch_bounds__(256) void k_scan2(const int* __restrict__ bsum, int* __restrict__ bofs){
    __shared__ int s[256];
    int t = threadIdx.x;
    s[t] = (t < NB_SCAN) ? bsum[t] : 0;
    __syncthreads();
    for (int off = 1; off < 256; off <<= 1){
        int v = s[t];
        int a = (t >= off) ? s[t - off] : 0;
        __syncthreads();
        s[t] = v + a;
        __syncthreads();
    }
    if (t < NB_SCAN) bofs[t] = (t > 0) ? s[t - 1] : 0;
}

__global__ __launch_bounds__(256) void k_scan3(const int* __restrict__ deg, const int* __restrict__ bofs,
                                               int* __restrict__ row_off, int* __restrict__ cursor){
    __shared__ int s[256];
    int t = threadIdx.x;
    int i = blockIdx.x * 256 + t;
    int d = (i < NN) ? deg[i] : 0;
    s[t] = d;
    __syncthreads();
    for (int off = 1; off < 256; off <<= 1){
        int v = s[t];
        int a = (t >= off) ? s[t - off] : 0;
        __syncthreads();
        s[t] = v + a;
        __syncthreads();
    }
    int excl = s[t] - d + bofs[blockIdx.x];
    if (i < NN){
        row_off[i] = excl; cursor[i] = excl;
        if (i == NN - 1) row_off[NN] = excl + d;
    }
}

__global__ __launch_bounds__(256) void k_scatter(const int* __restrict__ src, const int* __restrict__ dst,
                                                 int* __restrict__ cursor, int* __restrict__ csr, int E){
    int e = blockIdx.x * 256 + threadIdx.x;
    if (e < E){
        int d = dst[e];
        int pos = atomicAdd(&cursor[d], 1);
        csr[pos] = src[e];
    }
}

// ---------------- W1 transpose + bf16 split (hi/lo planes) ----------------
__global__ __launch_bounds__(256) void k_w1t(const float* __restrict__ W1,
                                             __bf16* __restrict__ w1h, __bf16* __restrict__ w1l){
    int c = blockIdx.x;                       // 0..63 output column
    for (int k = threadIdx.x; k < KPAD; k += 256){
        float v = (k < FIN) ? W1[(size_t)k * 64 + c] : 0.f;
        __bf16 hi = (__bf16)v;
        w1h[(size_t)c * KPAD + k] = hi;
        w1l[(size_t)c * KPAD + k] = (__bf16)(v - (float)hi);
    }
}

// ---------------- GEMM1: H = x @ W1 ----------------
// 64 rows/block, 4 waves; wave w owns cols w*16..w*16+15 (its own B tile, own acc -> no
// cross-wave reduce). A staged f32 via global_load_lds (width 4, 1 instr/row), double
// buffered K=64 blocks, LDS row stride 68 floats (272B: 16B-aligned, uniform banks).
__global__ __launch_bounds__(256, 3) void k_gemm1(const float* __restrict__ x,
    const __bf16* __restrict__ w1h, const __bf16* __restrict__ w1l,
    float* __restrict__ Hf, __bf16* __restrict__ Hb)
{
    __shared__ float As[2 * 64 * 68];        // 34.8 KB, [buf][row][68]
    const int tid  = threadIdx.x;
    const int w    = tid >> 6;
    const int lane = tid & 63;
    const int lr   = lane & 15;              // A row in tile / B,C col in tile
    const int lk   = lane >> 4;              // k-block (8 elems)
    const int rbase = blockIdx.x * 64;

    // per-wave staging: wave w stages rows w*16..w*16+15; lane l = k-offset l
    unsigned rowoff[16];
    #pragma unroll
    for (int i = 0; i < 16; ++i){
        int rg = rbase + w * 16 + i; if (rg >= NN) rg = NN - 1;
        rowoff[i] = (unsigned)rg * (unsigned)FIN + (unsigned)lane;
    }

    const __bf16* bh_p = w1h + (size_t)(w * 16 + lr) * KPAD + lk * 8;
    const __bf16* bl_p = w1l + (size_t)(w * 16 + lr) * KPAD + lk * 8;

    f32x4 acc[4] = {{0,0,0,0},{0,0,0,0},{0,0,0,0},{0,0,0,0}};

    // prologue: stage kb=0 into buf 0
    #pragma unroll
    for (int i = 0; i < 16; ++i)
        gld_lds4(x + rowoff[i], &As[(w * 16 + i) * 68]);
    __syncthreads();

    for (int kb = 0; kb < 22; ++kb){
        const int cur = kb & 1;
        if (kb < 21){
            const float* gsrc = x + (kb + 1) * 64;
            float* lb = &As[(1 - cur) * 4352];
            #pragma unroll
            for (int i = 0; i < 16; ++i)
                gld_lds4(gsrc + rowoff[i], lb + (w * 16 + i) * 68);
        }
        const int kA = kb * 64;
        bf16x8 bh0 = *(const bf16x8*)(bh_p + kA);
        bf16x8 bl0 = *(const bf16x8*)(bl_p + kA);
        bf16x8 bh1 = *(const bf16x8*)(bh_p + kA + 32);
        bf16x8 bl1 = *(const bf16x8*)(bl_p + kA + 32);
        const float* ab = &As[cur * 4352] + lk * 8;
        #pragma unroll
        for (int ks = 0; ks < 2; ++ks){
            bf16x8 bh = ks ? bh1 : bh0;
            bf16x8 bl = ks ? bl1 : bl0;
            #pragma unroll
            for (int t = 0; t < 4; ++t){
                const float* p = ab + (t * 16 + lr) * 68 + ks * 32;
                f32x4 v0 = *(const f32x4*)p;
                f32x4 v1 = *(const f32x4*)(p + 4);
                bf16x8 ah, al;
                #pragma unroll
                for (int e = 0; e < 4; ++e){
                    __bf16 h0 = (__bf16)v0[e];
                    ah[e]     = h0; al[e]     = (__bf16)(v0[e] - (float)h0);
                    __bf16 h1 = (__bf16)v1[e];
                    ah[e + 4] = h1; al[e + 4] = (__bf16)(v1[e] - (float)h1);
                }
                acc[t] = __builtin_amdgcn_mfma_f32_16x16x32_bf16(ah, bh, acc[t], 0, 0, 0);
                acc[t] = __builtin_amdgcn_mfma_f32_16x16x32_bf16(al, bh, acc[t], 0, 0, 0);
                acc[t] = __builtin_amdgcn_mfma_f32_16x16x32_bf16(ah, bl, acc[t], 0, 0, 0);
            }
        }
        __syncthreads();
    }

    // peeled masked tail: k 1408..1439 (valid < 1433), direct loads
    {
        bf16x8 bh = *(const bf16x8*)(bh_p + 1408);
        bf16x8 bl = *(const bf16x8*)(bl_p + 1408);
        #pragma unroll
        for (int t = 0; t < 4; ++t){
            int rg = rbase + t * 16 + lr; if (rg >= NN) rg = NN - 1;
            const float* xr = x + (size_t)rg * FIN;
            bf16x8 ah, al;
            #pragma unroll
            for (int e = 0; e < 8; ++e){
                int k = 1408 + lk * 8 + e;
                float v = (k < FIN) ? xr[k] : 0.f;
                __bf16 h = (__bf16)v;
                ah[e] = h; al[e] = (__bf16)(v - (float)h);
            }
            acc[t] = __builtin_amdgcn_mfma_f32_16x16x32_bf16(ah, bh, acc[t], 0, 0, 0);
            acc[t] = __builtin_amdgcn_mfma_f32_16x16x32_bf16(al, bh, acc[t], 0, 0, 0);
            acc[t] = __builtin_amdgcn_mfma_f32_16x16x32_bf16(ah, bl, acc[t], 0, 0, 0);
        }
    }

    // epilogue: C/D layout col=lane&15, row=(lane>>4)*4+reg
    #pragma unroll
    for (int t = 0; t < 4; ++t){
        #pragma unroll
        for (int r = 0; r < 4; ++r){
            int row = rbase + t * 16 + lk * 4 + r;
            if (row < NN){
                int col = w * 16 + lr;
                float v = acc[t][r];
                Hf[(size_t)row * 64 + col] = v;
                Hb[(size_t)row * 64 + col] = (__bf16)v;
            }
        }
    }
}

// ---------------- attention logits, layer 1 ----------------
__global__ __launch_bounds__(256) void k_alpha1(const float* __restrict__ Hf,
    const float* __restrict__ a_s, const float* __restrict__ a_d,
    float* __restrict__ as1, float* __restrict__ ad1)
{
    __shared__ float sa[64], sd[64];
    int tid = threadIdx.x;
    if (tid < 64){ sa[tid] = a_s[tid]; sd[tid] = a_d[tid]; }
    __syncthreads();
    int n = blockIdx.x * 256 + tid;
    if (n >= NN) return;
    const float* hr = Hf + (size_t)n * 64;
    #pragma unroll
    for (int h = 0; h < 8; ++h){
        float s = 0.f, d = 0.f;
        #pragma unroll
        for (int c = 0; c < 8; ++c){
            float v = hr[h * 8 + c];
            s = fmaf(v, sa[h * 8 + c], s);
            d = fmaf(v, sd[h * 8 + c], d);
        }
        as1[n * 8 + h] = s;
        ad1[n * 8 + h] = d;
    }
}

// ---------------- layer-1 edge pass: one wave per dst node, lane = out channel ----------------
__global__ __launch_bounds__(256) void k_layer1(const float* __restrict__ as1, const float* __restrict__ ad1,
    const __bf16* __restrict__ Hb, const int* __restrict__ row_off, const int* __restrict__ csr,
    const float* __restrict__ b1, float* __restrict__ x2)
{
    int d    = blockIdx.x * 4 + (threadIdx.x >> 6);   // grid is exactly N/4 blocks
    int lane = threadIdx.x & 63;
    int h    = lane >> 3;
    float adv = ad1[d * 8 + h];
    float e0  = leaky02(as1[d * 8 + h] + adv);        // self loop
    float p0  = __expf(e0 - 20.f);                    // fixed-offset softmax (e bounded << 20)
    float den = p0;
    float acc = p0 * (float)Hb[(size_t)d * 64 + lane];
    int beg = row_off[d], end = row_off[d + 1];
    for (int base = beg; base < end; base += 8){
        int cnt = end - base; if (cnt > 8) cnt = 8;
        int li  = lane & 7;
        int si  = csr[base + (li < cnt ? li : cnt - 1)];
        float pas[8]; float ph[8];
        #pragma unroll
        for (int t = 0; t < 8; ++t){
            if (t < cnt){
                int s  = __shfl(si, t, 64);
                pas[t] = as1[s * 8 + h];
                ph[t]  = (float)Hb[(size_t)s * 64 + lane];
            }
        }
        #pragma unroll
        for (int t = 0; t < 8; ++t){
            if (t < cnt){
                float e = leaky02(pas[t] + adv);
                float p = __expf(e - 20.f);
                den += p;
                acc  = fmaf(p, ph[t], acc);
            }
        }
    }
    float o = acc / den + b1[lane];
    x2[(size_t)d * 64 + lane] = (o > 0.f) ? o : (__expf(o) - 1.f);   // ELU fused
}

// ---------------- GEMM2 + attention logits, layer 2 ----------------
__global__ __launch_bounds__(256) void k_gemm2(const float* __restrict__ x2, const float* __restrict__ W2,
    const float* __restrict__ aw_in, const float* __restrict__ dw_in,
    float* __restrict__ h2, float* __restrict__ as2, float* __restrict__ ad2)
{
    __shared__ float w2s[448];
    __shared__ float aw[7], dw[7];
    int tid = threadIdx.x;
    for (int i = tid; i < 448; i += 256) w2s[i] = W2[i];
    if (tid < 7){ aw[tid] = aw_in[tid]; dw[tid] = dw_in[tid]; }
    __syncthreads();
    int n = blockIdx.x * 256 + tid;
    if (n >= NN) return;
    const float4* xp = (const float4*)(x2 + (size_t)n * 64);
    float acc[7] = {0.f,0.f,0.f,0.f,0.f,0.f,0.f};
    #pragma unroll
    for (int q = 0; q < 16; ++q){
        float4 v = xp[q];
        float vv[4] = {v.x, v.y, v.z, v.w};
        #pragma unroll
        for (int u = 0; u < 4; ++u){
            int k = q * 4 + u;
            #pragma unroll
            for (int c = 0; c < 7; ++c) acc[c] = fmaf(vv[u], w2s[k * 7 + c], acc[c]);
        }
    }
    float s = 0.f, d = 0.f;
    #pragma unroll
    for (int c = 0; c < 7; ++c){ s = fmaf(acc[c], aw[c], s); d = fmaf(acc[c], dw[c], d); }
    float* hp = h2 + (size_t)n * 8;
    #pragma unroll
    for (int c = 0; c < 7; ++c) hp[c] = acc[c];
    hp[7] = 0.f;
    as2[n] = s; ad2[n] = d;
}

// ---------------- layer-2 edge pass + bias + log_softmax: 8 lanes per node ----------------
__global__ __launch_bounds__(256) void k_layer2(const float* __restrict__ as2, const float* __restrict__ ad2,
    const float* __restrict__ h2, const int* __restrict__ row_off, const int* __restrict__ csr,
    const float* __restrict__ b2, float* __restrict__ out)
{
    int tid  = threadIdx.x;
    int node = blockIdx.x * 32 + (tid >> 3);
    int c    = tid & 7;
    if (node >= NN) return;
    float adv = ad2[node];
    float e0  = leaky02(as2[node] + adv);
    float p0  = __expf(e0 - 20.f);
    float den = p0;
    float acc = p0 * h2[(size_t)node * 8 + c];        // c==7 reads the 0 pad
    int beg = row_off[node], end = row_off[node + 1];
    for (int base = beg; base < end; base += 8){
        int cnt = end - base; if (cnt > 8) cnt = 8;
        int si  = csr[base + (c < cnt ? c : cnt - 1)];
        float pa[8]; float ph[8];
        #pragma unroll
        for (int t = 0; t < 8; ++t){
            if (t < cnt){
                int s = __shfl(si, t, 8);             // lane (group*8 + t)
                pa[t] = as2[s];
                ph[t] = h2[(size_t)s * 8 + c];
            }
        }
        #pragma unroll
        for (int t = 0; t < 8; ++t){
            if (t < cnt){
                float e = leaky02(pa[t] + adv);
                float p = __expf(e - 20.f);
                den += p;
                acc  = fmaf(p, ph[t], acc);
            }
        }
    }
    float v = (c < 7) ? (acc / den + b2[c]) : -1e30f;
    float m = v;
    m = fmaxf(m, __shfl_xor(m, 1, 64));
    m = fmaxf(m, __shfl_xor(m, 2, 64));
    m = fmaxf(m, __shfl_xor(m, 4, 64));
    float ex = (c < 7) ? __expf(v - m) : 0.f;
    float s7 = ex;
    s7 += __shfl_xor(s7, 1, 64);
    s7 += __shfl_xor(s7, 2, 64);
    s7 += __shfl_xor(s7, 4, 64);
    if (c < 7) out[(size_t)node * 7 + c] = v - m - __logf(s7);
}

// ---------------- launcher ----------------
extern "C" void kernel_launch(void* const* d_in, const int* in_sizes, int n_in,
                              void* d_out, int out_size, void* d_ws, size_t ws_size,
                              hipStream_t stream)
{
    (void)n_in; (void)out_size; (void)ws_size;
    const float* x      = (const float*)d_in[0];
    const int*   ei     = (const int*)d_in[1];
    const int    E      = in_sizes[1] / 2;
    const float* W1     = (const float*)d_in[2];
    const float* asrc1  = (const float*)d_in[3];
    const float* adst1  = (const float*)d_in[4];
    const float* b1     = (const float*)d_in[5];
    const float* W2     = (const float*)d_in[6];
    const float* asrc2  = (const float*)d_in[7];
    const float* adst2  = (const float*)d_in[8];
    const float* b2     = (const float*)d_in[9];
    float* out = (float*)d_out;

    char* p = (char*)d_ws;
    auto alloc = [&](size_t bytes) -> void* {
        void* r = (void*)p;
        p += (bytes + 255) & ~(size_t)255;
        return r;
    };
    int*    deg     = (int*)alloc((size_t)NN * 4);
    int*    row_off = (int*)alloc((size_t)(NN + 1) * 4);
    int*    cursor  = (int*)alloc((size_t)NN * 4);
    int*    bsum    = (int*)alloc((size_t)NB_SCAN * 4);
    int*    bofs    = (int*)alloc((size_t)NB_SCAN * 4);
    int*    csr     = (int*)alloc((size_t)E * 4);
    __bf16* w1h     = (__bf16*)alloc((size_t)64 * KPAD * 2);
    __bf16* w1l     = (__bf16*)alloc((size_t)64 * KPAD * 2);
    float*  Hf      = (float*)alloc((size_t)NN * 64 * 4);
    __bf16* Hb      = (__bf16*)alloc((size_t)NN * 64 * 2);
    float*  as1     = (float*)alloc((size_t)NN * 8 * 4);
    float*  ad1     = (float*)alloc((size_t)NN * 8 * 4);
    float*  x2      = (float*)alloc((size_t)NN * 64 * 4);
    float*  h2      = (float*)alloc((size_t)NN * 8 * 4);
    float*  as2     = (float*)alloc((size_t)NN * 4);
    float*  ad2     = (float*)alloc((size_t)NN * 4);

    const int* src = ei;
    const int* dst = ei + E;

    hipMemsetAsync(deg, 0, (size_t)NN * 4, stream);
    k_hist   <<<(E + 255) / 256, 256, 0, stream>>>(dst, deg, E);
    k_scan1  <<<NB_SCAN, 256, 0, stream>>>(deg, bsum);
    k_scan2  <<<1, 256, 0, stream>>>(bsum, bofs);
    k_scan3  <<<NB_SCAN, 256, 0, stream>>>(deg, bofs, row_off, cursor);
    k_scatter<<<(E + 255) / 256, 256, 0, stream>>>(src, dst, cursor, csr, E);
    k_w1t    <<<64, 256, 0, stream>>>(W1, w1h, w1l);
    k_gemm1  <<<(NN + 63) / 64, 256, 0, stream>>>(x, w1h, w1l, Hf, Hb);
    k_alpha1 <<<(NN + 255) / 256, 256, 0, stream>>>(Hf, asrc1, adst1, as1, ad1);
    k_layer1 <<<NN / 4, 256, 0, stream>>>(as1, ad1, Hb, row_off, csr, b1, x2);
    k_gemm2  <<<(NN + 255) / 256, 256, 0, stream>>>(x2, W2, asrc2, adst2, h2, as2, ad2);
    k_layer2 <<<(NN + 31) / 32, 256, 0, stream>>>(as2, ad2, h2, row_off, csr, b2, out);
}

// Round 5
// 421.453 us; speedup vs baseline: 1.6516x; 1.0856x over previous
//
#include <hip/hip_runtime.h>
#include <hip/hip_bf16.h>

static constexpr int NN      = 50000;
static constexpr int FIN     = 1433;
static constexpr int KPAD    = 1440;            // 45 * 32
static constexpr int NB_SCAN = (NN + 255) / 256; // 196

typedef __bf16 bf16x8 __attribute__((ext_vector_type(8)));
typedef float  f32x4  __attribute__((ext_vector_type(4)));

__device__ __forceinline__ float leaky02(float v){ return v >= 0.f ? v : 0.2f * v; }

// async global->LDS, 4 bytes/lane: lane l writes lds_base + l*4
__device__ __forceinline__ void gld_lds4(const float* g, float* l){
    __builtin_amdgcn_global_load_lds(
        (const __attribute__((address_space(1))) unsigned int*)g,
        (__attribute__((address_space(3))) unsigned int*)l, 4, 0, 0);
}

// ---------------- CSR build ----------------
// hist + per-edge rank in ONE atomic pass
__global__ __launch_bounds__(256) void k_rank(const int* __restrict__ dst, int* __restrict__ deg,
                                              int* __restrict__ rank, int E){
    int e = blockIdx.x * 256 + threadIdx.x;
    if (e < E) rank[e] = atomicAdd(&deg[dst[e]], 1);
}

__global__ __launch_bounds__(256) void k_scan1(const int* __restrict__ deg, int* __restrict__ bsum){
    __shared__ int red[256];
    int i = blockIdx.x * 256 + threadIdx.x;
    red[threadIdx.x] = (i < NN) ? deg[i] : 0;
    __syncthreads();
    for (int off = 128; off > 0; off >>= 1){
        if (threadIdx.x < off) red[threadIdx.x] += red[threadIdx.x + off];
        __syncthreads();
    }
    if (threadIdx.x == 0) bsum[blockIdx.x] = red[0];
}

__global__ __launch_bounds__(256) void k_scan2(const int* __restrict__ bsum, int* __restrict__ bofs){
    __shared__ int s[256];
    int t = threadIdx.x;
    s[t] = (t < NB_SCAN) ? bsum[t] : 0;
    __syncthreads();
    for (int off = 1; off < 256; off <<= 1){
        int v = s[t];
        int a = (t >= off) ? s[t - off] : 0;
        __syncthreads();
        s[t] = v + a;
        __syncthreads();
    }
    if (t < NB_SCAN) bofs[t] = (t > 0) ? s[t - 1] : 0;
}

__global__ __launch_bounds__(256) void k_scan3(const int* __restrict__ deg, const int* __restrict__ bofs,
                                               int* __restrict__ row_off){
    __shared__ int s[256];
    int t = threadIdx.x;
    int i = blockIdx.x * 256 + t;
    int d = (i < NN) ? deg[i] : 0;
    s[t] = d;
    __syncthreads();
    for (int off = 1; off < 256; off <<= 1){
        int v = s[t];
        int a = (t >= off) ? s[t - off] : 0;
        __syncthreads();
        s[t] = v + a;
        __syncthreads();
    }
    int excl = s[t] - d + bofs[blockIdx.x];
    if (i < NN){
        row_off[i] = excl;
        if (i == NN - 1) row_off[NN] = excl + d;
    }
}

// atomic-free scatter using precomputed rank
__global__ __launch_bounds__(256) void k_scatter(const int* __restrict__ src, const int* __restrict__ dst,
                                                 const int* __restrict__ rank, const int* __restrict__ row_off,
                                                 int* __restrict__ csr, int E){
    int e = blockIdx.x * 256 + threadIdx.x;
    if (e < E) csr[row_off[dst[e]] + rank[e]] = src[e];
}

// ---------------- W1 transpose + bf16 split (hi/lo planes) ----------------
__global__ __launch_bounds__(256) void k_w1t(const float* __restrict__ W1,
                                             __bf16* __restrict__ w1h, __bf16* __restrict__ w1l){
    int c = blockIdx.x;                       // 0..63 output column
    for (int k = threadIdx.x; k < KPAD; k += 256){
        float v = (k < FIN) ? W1[(size_t)k * 64 + c] : 0.f;
        __bf16 hi = (__bf16)v;
        w1h[(size_t)c * KPAD + k] = hi;
        w1l[(size_t)c * KPAD + k] = (__bf16)(v - (float)hi);
    }
}

// ---------------- GEMM1: H = x @ W1 (+ fused alpha1) ----------------
// 64 rows/block, 4 waves; wave w owns cols w*16..w*16+15. A staged f32 via
// global_load_lds (width 4), double-buffered K=64 blocks, LDS row stride 68 floats.
// Epilogue: H tile -> LDS -> as1/ad1 computed in-block (alpha1 fused).
__global__ __launch_bounds__(256, 3) void k_gemm1(const float* __restrict__ x,
    const __bf16* __restrict__ w1h, const __bf16* __restrict__ w1l,
    const float* __restrict__ a_s, const float* __restrict__ a_d,
    float* __restrict__ Hf, __bf16* __restrict__ Hb,
    float* __restrict__ as1, float* __restrict__ ad1)
{
    __shared__ float As[2 * 64 * 68];        // 34.8 KB, [buf][row][68]
    const int tid  = threadIdx.x;
    const int w    = tid >> 6;
    const int lane = tid & 63;
    const int lr   = lane & 15;              // A row in tile / B,C col in tile
    const int lk   = lane >> 4;              // k-block (8 elems)
    const int rbase = blockIdx.x * 64;

    // per-wave staging: wave w stages rows w*16..w*16+15; lane l = k-offset l
    unsigned rowoff[16];
    #pragma unroll
    for (int i = 0; i < 16; ++i){
        int rg = rbase + w * 16 + i; if (rg >= NN) rg = NN - 1;
        rowoff[i] = (unsigned)rg * (unsigned)FIN + (unsigned)lane;
    }

    const __bf16* bh_p = w1h + (size_t)(w * 16 + lr) * KPAD + lk * 8;
    const __bf16* bl_p = w1l + (size_t)(w * 16 + lr) * KPAD + lk * 8;

    f32x4 acc[4] = {{0,0,0,0},{0,0,0,0},{0,0,0,0},{0,0,0,0}};

    // prologue: stage kb=0 into buf 0
    #pragma unroll
    for (int i = 0; i < 16; ++i)
        gld_lds4(x + rowoff[i], &As[(w * 16 + i) * 68]);
    __syncthreads();

    for (int kb = 0; kb < 22; ++kb){
        const int cur = kb & 1;
        if (kb < 21){
            const float* gsrc = x + (kb + 1) * 64;
            float* lb = &As[(1 - cur) * 4352];
            #pragma unroll
            for (int i = 0; i < 16; ++i)
                gld_lds4(gsrc + rowoff[i], lb + (w * 16 + i) * 68);
        }
        const int kA = kb * 64;
        bf16x8 bh0 = *(const bf16x8*)(bh_p + kA);
        bf16x8 bl0 = *(const bf16x8*)(bl_p + kA);
        bf16x8 bh1 = *(const bf16x8*)(bh_p + kA + 32);
        bf16x8 bl1 = *(const bf16x8*)(bl_p + kA + 32);
        const float* ab = &As[cur * 4352] + lk * 8;
        #pragma unroll
        for (int ks = 0; ks < 2; ++ks){
            bf16x8 bh = ks ? bh1 : bh0;
            bf16x8 bl = ks ? bl1 : bl0;
            #pragma unroll
            for (int t = 0; t < 4; ++t){
                const float* p = ab + (t * 16 + lr) * 68 + ks * 32;
                f32x4 v0 = *(const f32x4*)p;
                f32x4 v1 = *(const f32x4*)(p + 4);
                bf16x8 ah, al;
                #pragma unroll
                for (int e = 0; e < 4; ++e){
                    __bf16 h0 = (__bf16)v0[e];
                    ah[e]     = h0; al[e]     = (__bf16)(v0[e] - (float)h0);
                    __bf16 h1 = (__bf16)v1[e];
                    ah[e + 4] = h1; al[e + 4] = (__bf16)(v1[e] - (float)h1);
                }
                acc[t] = __builtin_amdgcn_mfma_f32_16x16x32_bf16(ah, bh, acc[t], 0, 0, 0);
                acc[t] = __builtin_amdgcn_mfma_f32_16x16x32_bf16(al, bh, acc[t], 0, 0, 0);
                acc[t] = __builtin_amdgcn_mfma_f32_16x16x32_bf16(ah, bl, acc[t], 0, 0, 0);
            }
        }
        __syncthreads();
    }

    // peeled masked tail: k 1408..1439 (valid < 1433), direct loads
    {
        bf16x8 bh = *(const bf16x8*)(bh_p + 1408);
        bf16x8 bl = *(const bf16x8*)(bl_p + 1408);
        #pragma unroll
        for (int t = 0; t < 4; ++t){
            int rg = rbase + t * 16 + lr; if (rg >= NN) rg = NN - 1;
            const float* xr = x + (size_t)rg * FIN;
            bf16x8 ah, al;
            #pragma unroll
            for (int e = 0; e < 8; ++e){
                int k = 1408 + lk * 8 + e;
                float v = (k < FIN) ? xr[k] : 0.f;
                __bf16 h = (__bf16)v;
                ah[e] = h; al[e] = (__bf16)(v - (float)h);
            }
            acc[t] = __builtin_amdgcn_mfma_f32_16x16x32_bf16(ah, bh, acc[t], 0, 0, 0);
            acc[t] = __builtin_amdgcn_mfma_f32_16x16x32_bf16(al, bh, acc[t], 0, 0, 0);
            acc[t] = __builtin_amdgcn_mfma_f32_16x16x32_bf16(ah, bl, acc[t], 0, 0, 0);
        }
    }

    // epilogue part 1: H tile -> LDS (reuse As), plus global H stores from regs
    __syncthreads();    // all waves done with As
    #pragma unroll
    for (int t = 0; t < 4; ++t){
        #pragma unroll
        for (int r = 0; r < 4; ++r){
            int rib = t * 16 + lk * 4 + r;
            As[rib * 68 + (w * 16 + lr)] = acc[t][r];
            int row = rbase + rib;
            if (row < NN){
                int col = w * 16 + lr;
                float v = acc[t][r];
                Hf[(size_t)row * 64 + col] = v;
                Hb[(size_t)row * 64 + col] = (__bf16)v;
            }
        }
    }
    __syncthreads();
    // epilogue part 2: fused alpha1 — 512 (row, head) tasks over 256 threads
    #pragma unroll
    for (int it = 0; it < 2; ++it){
        int task = tid + it * 256;
        int row  = task >> 3;
        int hh   = task & 7;
        int grow = rbase + row;
        if (grow < NN){
            const float* hr = &As[row * 68 + hh * 8];
            float s = 0.f, dd = 0.f;
            #pragma unroll
            for (int c = 0; c < 8; ++c){
                float v = hr[c];
                s  = fmaf(v, a_s[hh * 8 + c], s);
                dd = fmaf(v, a_d[hh * 8 + c], dd);
            }
            as1[grow * 8 + hh] = s;
            ad1[grow * 8 + hh] = dd;
        }
    }
}

// ---------------- layer-1 edge pass: one wave per dst node, 16-deep pipelined ----------------
__global__ __launch_bounds__(256) void k_layer1(const float* __restrict__ as1, const float* __restrict__ ad1,
    const __bf16* __restrict__ Hb, const int* __restrict__ row_off, const int* __restrict__ csr,
    const float* __restrict__ b1, float* __restrict__ x2)
{
    int d    = blockIdx.x * 4 + (threadIdx.x >> 6);   // grid is exactly N/4 blocks
    int lane = threadIdx.x & 63;
    int h    = lane >> 3;
    int li   = lane & 15;
    float adv = ad1[d * 8 + h];
    float e0  = leaky02(as1[d * 8 + h] + adv);        // self loop
    float p0  = __expf(e0 - 20.f);                    // fixed-offset softmax (e bounded << 20)
    float den = p0;
    float acc = p0 * (float)Hb[(size_t)d * 64 + lane];
    int beg = row_off[d], end = row_off[d + 1];

    int base = beg;
    int cnt  = end - base; if (cnt > 16) cnt = 16;
    float pas[16], ph[16];
    if (cnt > 0){
        int si = csr[base + (li < cnt ? li : cnt - 1)];
        #pragma unroll
        for (int t = 0; t < 16; ++t) if (t < cnt){
            int s  = __shfl(si, t, 64);
            pas[t] = as1[s * 8 + h];
            ph[t]  = (float)Hb[(size_t)s * 64 + lane];
        }
    }
    while (cnt > 0){
        int nbase = base + cnt;
        int ncnt  = end - nbase; if (ncnt > 16) ncnt = 16;
        float npas[16], nph[16];
        if (ncnt > 0){
            int nsi = csr[nbase + (li < ncnt ? li : ncnt - 1)];
            #pragma unroll
            for (int t = 0; t < 16; ++t) if (t < ncnt){
                int s   = __shfl(nsi, t, 64);
                npas[t] = as1[s * 8 + h];
                nph[t]  = (float)Hb[(size_t)s * 64 + lane];
            }
        }
        #pragma unroll
        for (int t = 0; t < 16; ++t) if (t < cnt){
            float e = leaky02(pas[t] + adv);
            float p = __expf(e - 20.f);
            den += p;
            acc  = fmaf(p, ph[t], acc);
        }
        #pragma unroll
        for (int t = 0; t < 16; ++t){ pas[t] = npas[t]; ph[t] = nph[t]; }
        base = nbase; cnt = ncnt;
    }
    float o = acc / den + b1[lane];
    x2[(size_t)d * 64 + lane] = (o > 0.f) ? o : (__expf(o) - 1.f);   // ELU fused
}

// ---------------- GEMM2 + attention logits, layer 2 ----------------
__global__ __launch_bounds__(256) void k_gemm2(const float* __restrict__ x2, const float* __restrict__ W2,
    const float* __restrict__ aw_in, const float* __restrict__ dw_in,
    float* __restrict__ h2, float* __restrict__ as2, float* __restrict__ ad2)
{
    __shared__ float w2s[448];
    __shared__ float aw[7], dw[7];
    int tid = threadIdx.x;
    for (int i = tid; i < 448; i += 256) w2s[i] = W2[i];
    if (tid < 7){ aw[tid] = aw_in[tid]; dw[tid] = dw_in[tid]; }
    __syncthreads();
    int n = blockIdx.x * 256 + tid;
    if (n >= NN) return;
    const float4* xp = (const float4*)(x2 + (size_t)n * 64);
    float acc[7] = {0.f,0.f,0.f,0.f,0.f,0.f,0.f};
    #pragma unroll
    for (int q = 0; q < 16; ++q){
        float4 v = xp[q];
        float vv[4] = {v.x, v.y, v.z, v.w};
        #pragma unroll
        for (int u = 0; u < 4; ++u){
            int k = q * 4 + u;
            #pragma unroll
            for (int c = 0; c < 7; ++c) acc[c] = fmaf(vv[u], w2s[k * 7 + c], acc[c]);
        }
    }
    float s = 0.f, d = 0.f;
    #pragma unroll
    for (int c = 0; c < 7; ++c){ s = fmaf(acc[c], aw[c], s); d = fmaf(acc[c], dw[c], d); }
    float* hp = h2 + (size_t)n * 8;
    #pragma unroll
    for (int c = 0; c < 7; ++c) hp[c] = acc[c];
    hp[7] = 0.f;
    as2[n] = s; ad2[n] = d;
}

// ---------------- layer-2 edge pass + bias + log_softmax: 8 lanes per node ----------------
__global__ __launch_bounds__(256) void k_layer2(const float* __restrict__ as2, const float* __restrict__ ad2,
    const float* __restrict__ h2, const int* __restrict__ row_off, const int* __restrict__ csr,
    const float* __restrict__ b2, float* __restrict__ out)
{
    int tid  = threadIdx.x;
    int node = blockIdx.x * 32 + (tid >> 3);
    int c    = tid & 7;
    if (node >= NN) return;
    float adv = ad2[node];
    float e0  = leaky02(as2[node] + adv);
    float p0  = __expf(e0 - 20.f);
    float den = p0;
    float acc = p0 * h2[(size_t)node * 8 + c];        // c==7 reads the 0 pad
    int beg = row_off[node], end = row_off[node + 1];
    for (int base = beg; base < end; base += 8){
        int cnt = end - base; if (cnt > 8) cnt = 8;
        int si  = csr[base + (c < cnt ? c : cnt - 1)];
        float pa[8]; float ph[8];
        #pragma unroll
        for (int t = 0; t < 8; ++t){
            if (t < cnt){
                int s = __shfl(si, t, 8);             // lane (group*8 + t)
                pa[t] = as2[s];
                ph[t] = h2[(size_t)s * 8 + c];
            }
        }
        #pragma unroll
        for (int t = 0; t < 8; ++t){
            if (t < cnt){
                float e = leaky02(pa[t] + adv);
                float p = __expf(e - 20.f);
                den += p;
                acc  = fmaf(p, ph[t], acc);
            }
        }
    }
    float v = (c < 7) ? (acc / den + b2[c]) : -1e30f;
    float m = v;
    m = fmaxf(m, __shfl_xor(m, 1, 64));
    m = fmaxf(m, __shfl_xor(m, 2, 64));
    m = fmaxf(m, __shfl_xor(m, 4, 64));
    float ex = (c < 7) ? __expf(v - m) : 0.f;
    float s7 = ex;
    s7 += __shfl_xor(s7, 1, 64);
    s7 += __shfl_xor(s7, 2, 64);
    s7 += __shfl_xor(s7, 4, 64);
    if (c < 7) out[(size_t)node * 7 + c] = v - m - __logf(s7);
}

// ---------------- launcher ----------------
extern "C" void kernel_launch(void* const* d_in, const int* in_sizes, int n_in,
                              void* d_out, int out_size, void* d_ws, size_t ws_size,
                              hipStream_t stream)
{
    (void)n_in; (void)out_size; (void)ws_size;
    const float* x      = (const float*)d_in[0];
    const int*   ei     = (const int*)d_in[1];
    const int    E      = in_sizes[1] / 2;
    const float* W1     = (const float*)d_in[2];
    const float* asrc1  = (const float*)d_in[3];
    const float* adst1  = (const float*)d_in[4];
    const float* b1     = (const float*)d_in[5];
    const float* W2     = (const float*)d_in[6];
    const float* asrc2  = (const float*)d_in[7];
    const float* adst2  = (const float*)d_in[8];
    const float* b2     = (const float*)d_in[9];
    float* out = (float*)d_out;

    char* p = (char*)d_ws;
    auto alloc = [&](size_t bytes) -> void* {
        void* r = (void*)p;
        p += (bytes + 255) & ~(size_t)255;
        return r;
    };
    int*    deg     = (int*)alloc((size_t)NN * 4);
    int*    row_off = (int*)alloc((size_t)(NN + 1) * 4);
    int*    rank    = (int*)alloc((size_t)E * 4);
    int*    bsum    = (int*)alloc((size_t)NB_SCAN * 4);
    int*    bofs    = (int*)alloc((size_t)NB_SCAN * 4);
    int*    csr     = (int*)alloc((size_t)E * 4);
    __bf16* w1h     = (__bf16*)alloc((size_t)64 * KPAD * 2);
    __bf16* w1l     = (__bf16*)alloc((size_t)64 * KPAD * 2);
    float*  Hf      = (float*)alloc((size_t)NN * 64 * 4);
    __bf16* Hb      = (__bf16*)alloc((size_t)NN * 64 * 2);
    float*  as1     = (float*)alloc((size_t)NN * 8 * 4);
    float*  ad1     = (float*)alloc((size_t)NN * 8 * 4);
    float*  x2      = (float*)alloc((size_t)NN * 64 * 4);
    float*  h2      = (float*)alloc((size_t)NN * 8 * 4);
    float*  as2     = (float*)alloc((size_t)NN * 4);
    float*  ad2     = (float*)alloc((size_t)NN * 4);

    const int* src = ei;
    const int* dst = ei + E;

    hipMemsetAsync(deg, 0, (size_t)NN * 4, stream);
    k_rank   <<<(E + 255) / 256, 256, 0, stream>>>(dst, deg, rank, E);
    k_scan1  <<<NB_SCAN, 256, 0, stream>>>(deg, bsum);
    k_scan2  <<<1, 256, 0, stream>>>(bsum, bofs);
    k_scan3  <<<NB_SCAN, 256, 0, stream>>>(deg, bofs, row_off);
    k_scatter<<<(E + 255) / 256, 256, 0, stream>>>(src, dst, rank, row_off, csr, E);
    k_w1t    <<<64, 256, 0, stream>>>(W1, w1h, w1l);
    k_gemm1  <<<(NN + 63) / 64, 256, 0, stream>>>(x, w1h, w1l, asrc1, adst1, Hf, Hb, as1, ad1);
    k_layer1 <<<NN / 4, 256, 0, stream>>>(as1, ad1, Hb, row_off, csr, b1, x2);
    k_gemm2  <<<(NN + 255) / 256, 256, 0, stream>>>(x2, W2, asrc2, adst2, h2, as2, ad2);
    k_layer2 <<<(NN + 31) / 32, 256, 0, stream>>>(as2, ad2, h2, row_off, csr, b2, out);
}

// Round 6
// 375.325 us; speedup vs baseline: 1.8546x; 1.1229x over previous
//
#include <hip/hip_runtime.h>
#include <hip/hip_bf16.h>

static constexpr int NN      = 50000;
static constexpr int FIN     = 1433;
static constexpr int KPAD    = 1440;            // 45 * 32
static constexpr int NB_SCAN = (NN + 255) / 256; // 196

typedef __bf16 bf16x8 __attribute__((ext_vector_type(8)));
typedef float  f32x4  __attribute__((ext_vector_type(4)));

__device__ __forceinline__ float leaky02(float v){ return v >= 0.f ? v : 0.2f * v; }

// async global->LDS, 4 bytes/lane: lane l writes lds_base + l*4
__device__ __forceinline__ void gld_lds4(const float* g, float* l){
    __builtin_amdgcn_global_load_lds(
        (const __attribute__((address_space(1))) unsigned int*)g,
        (__attribute__((address_space(3))) unsigned int*)l, 4, 0, 0);
}

// ---------------- misc ----------------
__global__ __launch_bounds__(256) void k_zero(int* __restrict__ p, int n){
    int i = blockIdx.x * 256 + threadIdx.x;
    if (i < n) p[i] = 0;
}

// ---------------- CSR build ----------------
// hist + per-edge rank in ONE atomic pass
__global__ __launch_bounds__(256) void k_rank(const int* __restrict__ dst, int* __restrict__ deg,
                                              int* __restrict__ rank, int E){
    int e = blockIdx.x * 256 + threadIdx.x;
    if (e < E) rank[e] = atomicAdd(&deg[dst[e]], 1);
}

__global__ __launch_bounds__(256) void k_scan1(const int* __restrict__ deg, int* __restrict__ bsum){
    __shared__ int red[256];
    int i = blockIdx.x * 256 + threadIdx.x;
    red[threadIdx.x] = (i < NN) ? deg[i] : 0;
    __syncthreads();
    for (int off = 128; off > 0; off >>= 1){
        if (threadIdx.x < off) red[threadIdx.x] += red[threadIdx.x + off];
        __syncthreads();
    }
    if (threadIdx.x == 0) bsum[blockIdx.x] = red[0];
}

__global__ __launch_bounds__(256) void k_scan2(const int* __restrict__ bsum, int* __restrict__ bofs){
    __shared__ int s[256];
    int t = threadIdx.x;
    s[t] = (t < NB_SCAN) ? bsum[t] : 0;
    __syncthreads();
    for (int off = 1; off < 256; off <<= 1){
        int v = s[t];
        int a = (t >= off) ? s[t - off] : 0;
        __syncthreads();
        s[t] = v + a;
        __syncthreads();
    }
    if (t < NB_SCAN) bofs[t] = (t > 0) ? s[t - 1] : 0;
}

__global__ __launch_bounds__(256) void k_scan3(const int* __restrict__ deg, const int* __restrict__ bofs,
                                               int* __restrict__ row_off){
    __shared__ int s[256];
    int t = threadIdx.x;
    int i = blockIdx.x * 256 + t;
    int d = (i < NN) ? deg[i] : 0;
    s[t] = d;
    __syncthreads();
    for (int off = 1; off < 256; off <<= 1){
        int v = s[t];
        int a = (t >= off) ? s[t - off] : 0;
        __syncthreads();
        s[t] = v + a;
        __syncthreads();
    }
    int excl = s[t] - d + bofs[blockIdx.x];
    if (i < NN){
        row_off[i] = excl;
        if (i == NN - 1) row_off[NN] = excl + d;
    }
}

// atomic-free scatter using precomputed rank
__global__ __launch_bounds__(256) void k_scatter(const int* __restrict__ src, const int* __restrict__ dst,
                                                 const int* __restrict__ rank, const int* __restrict__ row_off,
                                                 int* __restrict__ csr, int E){
    int e = blockIdx.x * 256 + threadIdx.x;
    if (e < E) csr[row_off[dst[e]] + rank[e]] = src[e];
}

// ---------------- W1 transpose + bf16 split (hi/lo planes) ----------------
__global__ __launch_bounds__(256) void k_w1t(const float* __restrict__ W1,
                                             __bf16* __restrict__ w1h, __bf16* __restrict__ w1l){
    int c = blockIdx.x;                       // 0..63 output column
    for (int k = threadIdx.x; k < KPAD; k += 256){
        float v = (k < FIN) ? W1[(size_t)k * 64 + c] : 0.f;
        __bf16 hi = (__bf16)v;
        w1h[(size_t)c * KPAD + k] = hi;
        w1l[(size_t)c * KPAD + k] = (__bf16)(v - (float)hi);
    }
}

// ---------------- GEMM1: H = x @ W1 (+ fused alpha1), head-split outputs ----------------
// 64 rows/block, 4 waves; wave w owns cols w*16..w*16+15. A staged f32 via
// global_load_lds (width 4), double-buffered K=64 blocks, LDS row stride 68 floats.
// Outputs: Hb0/Hb1 [N][32] bf16 (head halves), asA/adA (heads 0-3), asB/adB (heads 4-7).
__global__ __launch_bounds__(256, 3) void k_gemm1(const float* __restrict__ x,
    const __bf16* __restrict__ w1h, const __bf16* __restrict__ w1l,
    const float* __restrict__ a_s, const float* __restrict__ a_d,
    __bf16* __restrict__ Hb0, __bf16* __restrict__ Hb1,
    float* __restrict__ asA, float* __restrict__ adA,
    float* __restrict__ asB, float* __restrict__ adB)
{
    __shared__ float As[2 * 64 * 68];        // 34.8 KB, [buf][row][68]
    const int tid  = threadIdx.x;
    const int w    = tid >> 6;
    const int lane = tid & 63;
    const int lr   = lane & 15;              // A row in tile / B,C col in tile
    const int lk   = lane >> 4;              // k-block (8 elems)
    const int rbase = blockIdx.x * 64;

    unsigned rowoff[16];
    #pragma unroll
    for (int i = 0; i < 16; ++i){
        int rg = rbase + w * 16 + i; if (rg >= NN) rg = NN - 1;
        rowoff[i] = (unsigned)rg * (unsigned)FIN + (unsigned)lane;
    }

    const __bf16* bh_p = w1h + (size_t)(w * 16 + lr) * KPAD + lk * 8;
    const __bf16* bl_p = w1l + (size_t)(w * 16 + lr) * KPAD + lk * 8;

    f32x4 acc[4] = {{0,0,0,0},{0,0,0,0},{0,0,0,0},{0,0,0,0}};

    #pragma unroll
    for (int i = 0; i < 16; ++i)
        gld_lds4(x + rowoff[i], &As[(w * 16 + i) * 68]);
    __syncthreads();

    for (int kb = 0; kb < 22; ++kb){
        const int cur = kb & 1;
        if (kb < 21){
            const float* gsrc = x + (kb + 1) * 64;
            float* lb = &As[(1 - cur) * 4352];
            #pragma unroll
            for (int i = 0; i < 16; ++i)
                gld_lds4(gsrc + rowoff[i], lb + (w * 16 + i) * 68);
        }
        const int kA = kb * 64;
        bf16x8 bh0 = *(const bf16x8*)(bh_p + kA);
        bf16x8 bl0 = *(const bf16x8*)(bl_p + kA);
        bf16x8 bh1 = *(const bf16x8*)(bh_p + kA + 32);
        bf16x8 bl1 = *(const bf16x8*)(bl_p + kA + 32);
        const float* ab = &As[cur * 4352] + lk * 8;
        #pragma unroll
        for (int ks = 0; ks < 2; ++ks){
            bf16x8 bh = ks ? bh1 : bh0;
            bf16x8 bl = ks ? bl1 : bl0;
            #pragma unroll
            for (int t = 0; t < 4; ++t){
                const float* p = ab + (t * 16 + lr) * 68 + ks * 32;
                f32x4 v0 = *(const f32x4*)p;
                f32x4 v1 = *(const f32x4*)(p + 4);
                bf16x8 ah, al;
                #pragma unroll
                for (int e = 0; e < 4; ++e){
                    __bf16 h0 = (__bf16)v0[e];
                    ah[e]     = h0; al[e]     = (__bf16)(v0[e] - (float)h0);
                    __bf16 h1 = (__bf16)v1[e];
                    ah[e + 4] = h1; al[e + 4] = (__bf16)(v1[e] - (float)h1);
                }
                acc[t] = __builtin_amdgcn_mfma_f32_16x16x32_bf16(ah, bh, acc[t], 0, 0, 0);
                acc[t] = __builtin_amdgcn_mfma_f32_16x16x32_bf16(al, bh, acc[t], 0, 0, 0);
                acc[t] = __builtin_amdgcn_mfma_f32_16x16x32_bf16(ah, bl, acc[t], 0, 0, 0);
            }
        }
        __syncthreads();
    }

    // peeled masked tail: k 1408..1439 (valid < 1433), direct loads
    {
        bf16x8 bh = *(const bf16x8*)(bh_p + 1408);
        bf16x8 bl = *(const bf16x8*)(bl_p + 1408);
        #pragma unroll
        for (int t = 0; t < 4; ++t){
            int rg = rbase + t * 16 + lr; if (rg >= NN) rg = NN - 1;
            const float* xr = x + (size_t)rg * FIN;
            bf16x8 ah, al;
            #pragma unroll
            for (int e = 0; e < 8; ++e){
                int k = 1408 + lk * 8 + e;
                float v = (k < FIN) ? xr[k] : 0.f;
                __bf16 h = (__bf16)v;
                ah[e] = h; al[e] = (__bf16)(v - (float)h);
            }
            acc[t] = __builtin_amdgcn_mfma_f32_16x16x32_bf16(ah, bh, acc[t], 0, 0, 0);
            acc[t] = __builtin_amdgcn_mfma_f32_16x16x32_bf16(al, bh, acc[t], 0, 0, 0);
            acc[t] = __builtin_amdgcn_mfma_f32_16x16x32_bf16(ah, bl, acc[t], 0, 0, 0);
        }
    }

    // epilogue part 1: H tile -> LDS (reuse As) + bf16 head-half stores
    __syncthreads();    // all waves done with As
    const int col = w * 16 + lr;
    __bf16* hbp = (col < 32) ? Hb0 : Hb1;
    const int cc = col & 31;
    #pragma unroll
    for (int t = 0; t < 4; ++t){
        #pragma unroll
        for (int r = 0; r < 4; ++r){
            int rib = t * 16 + lk * 4 + r;
            float v = acc[t][r];
            As[rib * 68 + col] = v;
            int row = rbase + rib;
            if (row < NN) hbp[(size_t)row * 32 + cc] = (__bf16)v;
        }
    }
    __syncthreads();
    // epilogue part 2: fused alpha1 — 512 (row, head) tasks over 256 threads
    #pragma unroll
    for (int it = 0; it < 2; ++it){
        int task = tid + it * 256;
        int row  = task >> 3;
        int hh   = task & 7;
        int grow = rbase + row;
        if (grow < NN){
            const float* hr = &As[row * 68 + hh * 8];
            float s = 0.f, dd = 0.f;
            #pragma unroll
            for (int c = 0; c < 8; ++c){
                float v = hr[c];
                s  = fmaf(v, a_s[hh * 8 + c], s);
                dd = fmaf(v, a_d[hh * 8 + c], dd);
            }
            if (hh < 4){ asA[grow * 4 + hh] = s;       adA[grow * 4 + hh] = dd; }
            else       { asB[grow * 4 + (hh - 4)] = s; adB[grow * 4 + (hh - 4)] = dd; }
        }
    }
}

// ---------------- layer-1 edge pass, one head-half per dispatch ----------------
// wave = 1 dst node; lane = (edge slot e2 = lane>>5) x (channel c = lane&31).
// Random working set per pass: HbP 3.2MB + asP 0.8MB -> fits per-XCD L2.
__global__ __launch_bounds__(256, 6) void k_layer1p(const float* __restrict__ asP, const float* __restrict__ adP,
    const __bf16* __restrict__ HbP, const int* __restrict__ row_off, const int* __restrict__ csr,
    const float* __restrict__ b1P, float* __restrict__ x2, int colbase)
{
    const int d    = blockIdx.x * 4 + (threadIdx.x >> 6);
    const int lane = threadIdx.x & 63;
    const int e2   = lane >> 5;
    const int c    = lane & 31;
    const int h    = c >> 3;
    const float adv = adP[d * 4 + h];
    float den, acc;
    {
        float e0 = leaky02(asP[d * 4 + h] + adv);
        float p0 = __expf(e0 - 20.f);            // fixed-offset softmax (e bounded << 20)
        den = e2 ? 0.f : p0;
        acc = e2 ? 0.f : p0 * (float)HbP[(size_t)d * 32 + c];
    }
    const int beg = row_off[d], end = row_off[d + 1];
    const int nfull = (end - beg) >> 4;
    const int* cp = csr + beg + e2;

    float pa[8], hb[8];
    if (nfull > 0){
        #pragma unroll
        for (int t = 0; t < 8; ++t){
            int s = __builtin_nontemporal_load(cp + 2 * t);
            pa[t] = asP[s * 4 + h];
            hb[t] = (float)HbP[(size_t)s * 32 + c];
        }
        for (int b = 1; b < nfull; ++b){
            float npa[8], nhb[8];
            const int* cpb = cp + b * 16;
            #pragma unroll
            for (int t = 0; t < 8; ++t){
                int s = __builtin_nontemporal_load(cpb + 2 * t);
                npa[t] = asP[s * 4 + h];
                nhb[t] = (float)HbP[(size_t)s * 32 + c];
            }
            #pragma unroll
            for (int t = 0; t < 8; ++t){
                float e = leaky02(pa[t] + adv);
                float p = __expf(e - 20.f);
                den += p; acc = fmaf(p, hb[t], acc);
            }
            #pragma unroll
            for (int t = 0; t < 8; ++t){ pa[t] = npa[t]; hb[t] = nhb[t]; }
        }
        #pragma unroll
        for (int t = 0; t < 8; ++t){
            float e = leaky02(pa[t] + adv);
            float p = __expf(e - 20.f);
            den += p; acc = fmaf(p, hb[t], acc);
        }
    }
    // tail (0..15 edges), masked
    {
        int tb = beg + nfull * 16;
        int tc = end - tb;
        if (tc > 0){
            #pragma unroll
            for (int t = 0; t < 8; ++t){
                int j = 2 * t + e2;
                int idx = tb + (j < tc ? j : tc - 1);
                int s = __builtin_nontemporal_load(csr + idx);
                float pav = asP[s * 4 + h];
                float hbv = (float)HbP[(size_t)s * 32 + c];
                if (j < tc){
                    float e = leaky02(pav + adv);
                    float p = __expf(e - 20.f);
                    den += p; acc = fmaf(p, hbv, acc);
                }
            }
        }
    }
    acc += __shfl_xor(acc, 32, 64);
    den += __shfl_xor(den, 32, 64);
    if (e2 == 0){
        float o = acc / den + b1P[c];
        x2[(size_t)d * 64 + colbase + c] = (o > 0.f) ? o : (__expf(o) - 1.f);   // ELU fused
    }
}

// ---------------- GEMM2 + attention logits, layer 2 ----------------
__global__ __launch_bounds__(256) void k_gemm2(const float* __restrict__ x2, const float* __restrict__ W2,
    const float* __restrict__ aw_in, const float* __restrict__ dw_in,
    float* __restrict__ h2, float* __restrict__ as2, float* __restrict__ ad2)
{
    __shared__ float w2s[448];
    __shared__ float aw[7], dw[7];
    int tid = threadIdx.x;
    for (int i = tid; i < 448; i += 256) w2s[i] = W2[i];
    if (tid < 7){ aw[tid] = aw_in[tid]; dw[tid] = dw_in[tid]; }
    __syncthreads();
    int n = blockIdx.x * 256 + tid;
    if (n >= NN) return;
    const float4* xp = (const float4*)(x2 + (size_t)n * 64);
    float acc[7] = {0.f,0.f,0.f,0.f,0.f,0.f,0.f};
    #pragma unroll
    for (int q = 0; q < 16; ++q){
        float4 v = xp[q];
        float vv[4] = {v.x, v.y, v.z, v.w};
        #pragma unroll
        for (int u = 0; u < 4; ++u){
            int k = q * 4 + u;
            #pragma unroll
            for (int c = 0; c < 7; ++c) acc[c] = fmaf(vv[u], w2s[k * 7 + c], acc[c]);
        }
    }
    float s = 0.f, d = 0.f;
    #pragma unroll
    for (int c = 0; c < 7; ++c){ s = fmaf(acc[c], aw[c], s); d = fmaf(acc[c], dw[c], d); }
    float* hp = h2 + (size_t)n * 8;
    #pragma unroll
    for (int c = 0; c < 7; ++c) hp[c] = acc[c];
    hp[7] = 0.f;
    as2[n] = s; ad2[n] = d;
}

// ---------------- layer-2 edge pass + bias + log_softmax: 8 lanes per node ----------------
__global__ __launch_bounds__(256) void k_layer2(const float* __restrict__ as2, const float* __restrict__ ad2,
    const float* __restrict__ h2, const int* __restrict__ row_off, const int* __restrict__ csr,
    const float* __restrict__ b2, float* __restrict__ out)
{
    int tid  = threadIdx.x;
    int node = blockIdx.x * 32 + (tid >> 3);
    int c    = tid & 7;
    if (node >= NN) return;
    float adv = ad2[node];
    float e0  = leaky02(as2[node] + adv);
    float p0  = __expf(e0 - 20.f);
    float den = p0;
    float acc = p0 * h2[(size_t)node * 8 + c];        // c==7 reads the 0 pad
    int beg = row_off[node], end = row_off[node + 1];
    for (int base = beg; base < end; base += 8){
        int cnt = end - base; if (cnt > 8) cnt = 8;
        int si  = csr[base + (c < cnt ? c : cnt - 1)];
        float pa[8]; float ph[8];
        #pragma unroll
        for (int t = 0; t < 8; ++t){
            if (t < cnt){
                int s = __shfl(si, t, 8);             // lane (group*8 + t)
                pa[t] = as2[s];
                ph[t] = h2[(size_t)s * 8 + c];
            }
        }
        #pragma unroll
        for (int t = 0; t < 8; ++t){
            if (t < cnt){
                float e = leaky02(pa[t] + adv);
                float p = __expf(e - 20.f);
                den += p;
                acc  = fmaf(p, ph[t], acc);
            }
        }
    }
    float v = (c < 7) ? (acc / den + b2[c]) : -1e30f;
    float m = v;
    m = fmaxf(m, __shfl_xor(m, 1, 64));
    m = fmaxf(m, __shfl_xor(m, 2, 64));
    m = fmaxf(m, __shfl_xor(m, 4, 64));
    float ex = (c < 7) ? __expf(v - m) : 0.f;
    float s7 = ex;
    s7 += __shfl_xor(s7, 1, 64);
    s7 += __shfl_xor(s7, 2, 64);
    s7 += __shfl_xor(s7, 4, 64);
    if (c < 7) out[(size_t)node * 7 + c] = v - m - __logf(s7);
}

// ---------------- launcher ----------------
extern "C" void kernel_launch(void* const* d_in, const int* in_sizes, int n_in,
                              void* d_out, int out_size, void* d_ws, size_t ws_size,
                              hipStream_t stream)
{
    (void)n_in; (void)out_size; (void)ws_size;
    const float* x      = (const float*)d_in[0];
    const int*   ei     = (const int*)d_in[1];
    const int    E      = in_sizes[1] / 2;
    const float* W1     = (const float*)d_in[2];
    const float* asrc1  = (const float*)d_in[3];
    const float* adst1  = (const float*)d_in[4];
    const float* b1     = (const float*)d_in[5];
    const float* W2     = (const float*)d_in[6];
    const float* asrc2  = (const float*)d_in[7];
    const float* adst2  = (const float*)d_in[8];
    const float* b2     = (const float*)d_in[9];
    float* out = (float*)d_out;

    char* p = (char*)d_ws;
    auto alloc = [&](size_t bytes) -> void* {
        void* r = (void*)p;
        p += (bytes + 255) & ~(size_t)255;
        return r;
    };
    int*    deg     = (int*)alloc((size_t)NN * 4);
    int*    row_off = (int*)alloc((size_t)(NN + 1) * 4);
    int*    rank    = (int*)alloc((size_t)E * 4);
    int*    bsum    = (int*)alloc((size_t)NB_SCAN * 4);
    int*    bofs    = (int*)alloc((size_t)NB_SCAN * 4);
    int*    csr     = (int*)alloc((size_t)E * 4);
    __bf16* w1h     = (__bf16*)alloc((size_t)64 * KPAD * 2);
    __bf16* w1l     = (__bf16*)alloc((size_t)64 * KPAD * 2);
    __bf16* Hb0     = (__bf16*)alloc((size_t)NN * 32 * 2);
    __bf16* Hb1     = (__bf16*)alloc((size_t)NN * 32 * 2);
    float*  asA     = (float*)alloc((size_t)NN * 4 * 4);
    float*  adA     = (float*)alloc((size_t)NN * 4 * 4);
    float*  asB     = (float*)alloc((size_t)NN * 4 * 4);
    float*  adB     = (float*)alloc((size_t)NN * 4 * 4);
    float*  x2      = (float*)alloc((size_t)NN * 64 * 4);
    float*  h2      = (float*)alloc((size_t)NN * 8 * 4);
    float*  as2     = (float*)alloc((size_t)NN * 4);
    float*  ad2     = (float*)alloc((size_t)NN * 4);

    const int* src = ei;
    const int* dst = ei + E;

    k_zero   <<<(NN + 255) / 256, 256, 0, stream>>>(deg, NN);
    k_rank   <<<(E + 255) / 256, 256, 0, stream>>>(dst, deg, rank, E);
    k_scan1  <<<NB_SCAN, 256, 0, stream>>>(deg, bsum);
    k_scan2  <<<1, 256, 0, stream>>>(bsum, bofs);
    k_scan3  <<<NB_SCAN, 256, 0, stream>>>(deg, bofs, row_off);
    k_scatter<<<(E + 255) / 256, 256, 0, stream>>>(src, dst, rank, row_off, csr, E);
    k_w1t    <<<64, 256, 0, stream>>>(W1, w1h, w1l);
    k_gemm1  <<<(NN + 63) / 64, 256, 0, stream>>>(x, w1h, w1l, asrc1, adst1,
                                                  Hb0, Hb1, asA, adA, asB, adB);
    k_layer1p<<<NN / 4, 256, 0, stream>>>(asA, adA, Hb0, row_off, csr, b1,      x2, 0);
    k_layer1p<<<NN / 4, 256, 0, stream>>>(asB, adB, Hb1, row_off, csr, b1 + 32, x2, 32);
    k_gemm2  <<<(NN + 255) / 256, 256, 0, stream>>>(x2, W2, asrc2, adst2, h2, as2, ad2);
    k_layer2 <<<(NN + 31) / 32, 256, 0, stream>>>(as2, ad2, h2, row_off, csr, b2, out);
}